// Round 25
// baseline (628.081 us; speedup 1.0000x reference)
//
#include <hip/hip_runtime.h>

// ---------------- constants ----------------
namespace {
constexpr int Bn   = 2;
constexpr int Cc   = 256;
constexpr int Ntok = 5376;      // 4096 + 1024 + 256
constexpr int Ffn  = 1024;
constexpr int HW2  = 128 * 128; // res2 spatial
constexpr float EPSf = 1e-5f;
constexpr int WL   = 729088;    // bf16 elems per layer weight block
}

typedef __attribute__((ext_vector_type(8))) short bf16x8;
typedef __attribute__((ext_vector_type(4))) float f32x4;

__device__ inline unsigned short f2bf(float x) {
  unsigned u = __float_as_uint(x);
  return (unsigned short)((u + 0x7fffu + ((u >> 16) & 1u)) >> 16);
}
__device__ inline float bf2f(unsigned short b) {
  return __uint_as_float((unsigned)b << 16);
}

__device__ inline void store_chunk_f32(unsigned short* lds, int row, int g,
                                       const float* v8) {
  int sg = g ^ (row & 7);
  unsigned short tmp[8];
#pragma unroll
  for (int j = 0; j < 8; j++) tmp[j] = f2bf(v8[j]);
  *reinterpret_cast<uint4*>(&lds[row * 64 + sg * 8]) =
      *reinterpret_cast<const uint4*>(tmp);
}
__device__ inline void store_chunk_bf(unsigned short* lds, int row, int g,
                                      uint4 v) {
  int sg = g ^ (row & 7);
  *reinterpret_cast<uint4*>(&lds[row * 64 + sg * 8]) = v;
}

// ---------------- fused setup: flatten+PE (blocks 0..1023) + weight prep ----------------
__global__ __launch_bounds__(256) void setup_all(
    const float* __restrict__ r3, const float* __restrict__ r4,
    const float* __restrict__ r5, const float* __restrict__ lemb,
    float* __restrict__ x, unsigned short* __restrict__ xb,
    unsigned short* __restrict__ qb, unsigned short* __restrict__ peb,
    const float* __restrict__ valW, const float* __restrict__ offW,
    const float* __restrict__ awW, const float* __restrict__ outW,
    const float* __restrict__ fc1W, const float* __restrict__ fc2W,
    const float* __restrict__ latW, const float* __restrict__ smW,
    unsigned short* __restrict__ wbf, unsigned short* __restrict__ wlat,
    unsigned short* __restrict__ wt) {
  int bx = blockIdx.x;
  int tid = threadIdx.x;
  if (bx < 1024) {
    const int NPC = Ntok * Cc;
    for (int i = bx * 256 + tid; i < Bn * NPC; i += 1024 * 256) {
      int c = i & 255;
      int rest = i >> 8;
      int p = rest % Ntok;
      int b = rest / Ntok;
      int li = (p < 4096) ? 0 : ((p < 5120) ? 1 : 2);
      int start = (li == 0) ? 0 : ((li == 1) ? 4096 : 5120);
      int size = (li == 0) ? 4096 : ((li == 1) ? 1024 : 256);
      const float* f = (li == 0) ? r3 : ((li == 1) ? r4 : r5);
      int sp = p - start;
      int shift = 6 - li;
      int W = 64 >> li;
      int iy = sp >> shift;
      int ix = sp & (W - 1);
      int j = c & 63;
      int sel = c >> 6;
      float div = expf(-(float)j * (9.210340371976184f / 64.f));
      float coord = (sel < 2) ? (float)iy : (float)ix;
      float arg = coord * div;
      unsigned short pe16 = f2bf((sel & 1) ? cosf(arg) : sinf(arg));
      float v = f[((size_t)(b * Cc + c)) * size + sp] + lemb[li * Cc + c];
      x[i] = v;
      xb[i] = f2bf(v);
      qb[i] = f2bf(v + bf2f(pe16));
      peb[i - b * NPC] = pe16;
    }
    return;
  }
  int b2 = bx - 1024;
  if (b2 < 4272) {
    int i4 = b2 * 256 + tid;  // < 1093632
    int l = i4 / 182272;
    int e = (i4 - l * 182272) * 4;
    const float* src;
    int off;
    if (e < 65536) { src = valW + (size_t)l * 65536; off = e; }
    else if (e < 139264) {
      int j = e - 65536;
      if (j < 49152) { src = offW + (size_t)l * 49152; off = j; }
      else { src = awW + (size_t)l * 24576; off = j - 49152; }
    } else if (e < 204800) { src = outW + (size_t)l * 65536; off = e - 139264; }
    else if (e < 466944) { src = fc1W + (size_t)l * 262144; off = e - 204800; }
    else { src = fc2W + (size_t)l * 262144; off = e - 466944; }
    float4 v = *reinterpret_cast<const float4*>(&src[off]);
    unsigned short t[4] = {f2bf(v.x), f2bf(v.y), f2bf(v.z), f2bf(v.w)};
    *reinterpret_cast<uint2*>(&wbf[(size_t)l * WL + e]) =
        *reinterpret_cast<const uint2*>(t);
  } else if (b2 < 4336) {
    int e = ((b2 - 4272) * 256 + tid) * 4;  // < 65536
    float4 v = *reinterpret_cast<const float4*>(&latW[e]);
    unsigned short t[4] = {f2bf(v.x), f2bf(v.y), f2bf(v.z), f2bf(v.w)};
    *reinterpret_cast<uint2*>(&wlat[e]) = *reinterpret_cast<const uint2*>(t);
  } else {
    int i = (b2 - 4336) * 256 + tid;  // < 589824
    int o = i / 2304;
    int r = i - o * 2304;
    int tap = r >> 8;
    int c = r & 255;
    wt[i] = f2bf(smW[((size_t)(o * 256 + c)) * 9 + tap]);
  }
}

// =================================================================
// Generic MFMA GEMM: out(M,N) = A(M,K)bf16 @ Wb(N,K)^T bf16 + bias.
// BM=64, BN=128, BK=64, 256 threads = 4 waves (2x2), 16x16x32 mfma.
// =================================================================
template <int ACT, int OBF>
__global__ __launch_bounds__(256) void gemm_mfma_b(
    const unsigned short* __restrict__ A, const unsigned short* __restrict__ Wb,
    const float* __restrict__ bias, void* __restrict__ outp,
    int M, int N, int K, int nbx) {
  __shared__ unsigned short As[64 * 64];
  __shared__ unsigned short Ws[128 * 64];
  const int tid = threadIdx.x;
  const int nwg = gridDim.x;
  const int swz = (blockIdx.x & 7) * (nwg >> 3) + (blockIdx.x >> 3);
  const int m0 = (swz / nbx) * 64, n0 = (swz % nbx) * 128;
  const int wid = tid >> 6, lane = tid & 63;
  const int wm = wid >> 1, wn = wid & 1;
  const int lr = lane & 15, lh = lane >> 4;
  const int r8 = tid >> 3, g8 = tid & 7;
  f32x4 acc[2][4];
#pragma unroll
  for (int i = 0; i < 2; i++)
#pragma unroll
    for (int j = 0; j < 4; j++) acc[i][j] = f32x4{0.f, 0.f, 0.f, 0.f};

  uint4 ra[2], rw[4];
  const uint4 z4 = uint4{0, 0, 0, 0};
#pragma unroll
  for (int i = 0; i < 2; i++)
    ra[i] = *reinterpret_cast<const uint4*>(
        &A[(size_t)(m0 + r8 + i * 32) * K + g8 * 8]);
#pragma unroll
  for (int i = 0; i < 4; i++) {
    int n = n0 + r8 + i * 32;
    rw[i] = (n < N) ? *reinterpret_cast<const uint4*>(
                          &Wb[(size_t)n * K + g8 * 8])
                    : z4;
  }

  for (int k0 = 0; k0 < K; k0 += 64) {
    if (k0) __syncthreads();
#pragma unroll
    for (int i = 0; i < 2; i++) store_chunk_bf(As, r8 + i * 32, g8, ra[i]);
#pragma unroll
    for (int i = 0; i < 4; i++) store_chunk_bf(Ws, r8 + i * 32, g8, rw[i]);
    __syncthreads();
    int kn = k0 + 64;
    if (kn < K) {
#pragma unroll
      for (int i = 0; i < 2; i++)
        ra[i] = *reinterpret_cast<const uint4*>(
            &A[(size_t)(m0 + r8 + i * 32) * K + kn + g8 * 8]);
#pragma unroll
      for (int i = 0; i < 4; i++) {
        int n = n0 + r8 + i * 32;
        rw[i] = (n < N) ? *reinterpret_cast<const uint4*>(
                              &Wb[(size_t)n * K + kn + g8 * 8])
                        : z4;
      }
    }
    bf16x8 af[2][2], bfr[4][2];
#pragma unroll
    for (int mi = 0; mi < 2; mi++) {
      int r = wm * 32 + mi * 16 + lr;
#pragma unroll
      for (int s = 0; s < 2; s++) {
        int g = s * 4 + lh;
        af[mi][s] =
            *reinterpret_cast<const bf16x8*>(&As[r * 64 + (g ^ (r & 7)) * 8]);
      }
    }
#pragma unroll
    for (int nj = 0; nj < 4; nj++) {
      int r = wn * 64 + nj * 16 + lr;
#pragma unroll
      for (int s = 0; s < 2; s++) {
        int g = s * 4 + lh;
        bfr[nj][s] =
            *reinterpret_cast<const bf16x8*>(&Ws[r * 64 + (g ^ (r & 7)) * 8]);
      }
    }
#pragma unroll
    for (int mi = 0; mi < 2; mi++)
#pragma unroll
      for (int nj = 0; nj < 4; nj++) {
        acc[mi][nj] = __builtin_amdgcn_mfma_f32_16x16x32_bf16(
            af[mi][0], bfr[nj][0], acc[mi][nj], 0, 0, 0);
        acc[mi][nj] = __builtin_amdgcn_mfma_f32_16x16x32_bf16(
            af[mi][1], bfr[nj][1], acc[mi][nj], 0, 0, 0);
      }
  }
#pragma unroll
  for (int mi = 0; mi < 2; mi++) {
    int row = m0 + wm * 32 + mi * 16 + lh * 4;
#pragma unroll
    for (int nj = 0; nj < 4; nj++) {
      int col = n0 + wn * 64 + nj * 16 + lr;
      if (col >= N) continue;
      float b = bias[col];
#pragma unroll
      for (int r = 0; r < 4; r++) {
        float v = acc[mi][nj][r] + b;
        if (ACT) v = fmaxf(v, 0.f);
        if (OBF)
          ((unsigned short*)outp)[(size_t)(row + r) * N + col] = f2bf(v);
        else
          ((float*)outp)[(size_t)(row + r) * N + col] = v;
      }
    }
  }
}

// =================================================================
// GEMM (N=256 full rows) + residual + LayerNorm fused epilogue.
// BM=16, BN=256, grid 672. TOKOUT: also write NCHW token outputs.
// =================================================================
template <int WRITEQ, int TOKOUT>
__global__ __launch_bounds__(256) void gemm_ln(
    const unsigned short* __restrict__ A, const unsigned short* __restrict__ Wb,
    const float* __restrict__ bias, const float* __restrict__ g,
    const float* __restrict__ bta, float* __restrict__ x,
    unsigned short* __restrict__ xb, const unsigned short* __restrict__ peb,
    unsigned short* __restrict__ qb, int K, float* __restrict__ o3,
    float* __restrict__ o4, float* __restrict__ o5) {
  __shared__ unsigned short As[16 * 64];
  __shared__ unsigned short Ws[256 * 64];
  __shared__ float pred[4][16];
  __shared__ float qred[4][16];
  const int tid = threadIdx.x;
  const int swz = (blockIdx.x & 7) * 84 + (blockIdx.x >> 3);  // grid 672
  const int m0 = swz * 16;
  const int wid = tid >> 6, lane = tid & 63;  // wid = column quarter
  const int lr = lane & 15, lh = lane >> 4;
  const int r8 = tid >> 3, g8 = tid & 7;
  f32x4 acc[4];
#pragma unroll
  for (int i = 0; i < 4; i++) acc[i] = f32x4{0.f, 0.f, 0.f, 0.f};

  uint4 ra, rw[8];
  if (tid < 128)
    ra = *reinterpret_cast<const uint4*>(&A[(size_t)(m0 + r8) * K + g8 * 8]);
#pragma unroll
  for (int i = 0; i < 8; i++)
    rw[i] = *reinterpret_cast<const uint4*>(
        &Wb[(size_t)(r8 + i * 32) * K + g8 * 8]);

  for (int k0 = 0; k0 < K; k0 += 64) {
    if (k0) __syncthreads();
    if (tid < 128) store_chunk_bf(As, r8, g8, ra);
#pragma unroll
    for (int i = 0; i < 8; i++) store_chunk_bf(Ws, r8 + i * 32, g8, rw[i]);
    __syncthreads();
    int kn = k0 + 64;
    if (kn < K) {
      if (tid < 128)
        ra = *reinterpret_cast<const uint4*>(
            &A[(size_t)(m0 + r8) * K + kn + g8 * 8]);
#pragma unroll
      for (int i = 0; i < 8; i++)
        rw[i] = *reinterpret_cast<const uint4*>(
            &Wb[(size_t)(r8 + i * 32) * K + kn + g8 * 8]);
    }
    bf16x8 af[2];
    {
      int r = lr;
#pragma unroll
      for (int s = 0; s < 2; s++) {
        int gg2 = s * 4 + lh;
        af[s] =
            *reinterpret_cast<const bf16x8*>(&As[r * 64 + (gg2 ^ (r & 7)) * 8]);
      }
    }
#pragma unroll
    for (int nt = 0; nt < 4; nt++) {
      int r = wid * 64 + nt * 16 + lr;
      bf16x8 b0 =
          *reinterpret_cast<const bf16x8*>(&Ws[r * 64 + (lh ^ (r & 7)) * 8]);
      bf16x8 b1 = *reinterpret_cast<const bf16x8*>(
          &Ws[r * 64 + ((4 + lh) ^ (r & 7)) * 8]);
      acc[nt] =
          __builtin_amdgcn_mfma_f32_16x16x32_bf16(af[0], b0, acc[nt], 0, 0, 0);
      acc[nt] =
          __builtin_amdgcn_mfma_f32_16x16x32_bf16(af[1], b1, acc[nt], 0, 0, 0);
    }
  }

  const int rowl = lh * 4;
#pragma unroll
  for (int nt = 0; nt < 4; nt++) {
    int col = wid * 64 + nt * 16 + lr;
    float bs = bias[col];
#pragma unroll
    for (int r = 0; r < 4; r++)
      acc[nt][r] += bs + x[(size_t)(m0 + rowl + r) * 256 + col];
  }
  float sum[4];
#pragma unroll
  for (int r = 0; r < 4; r++) {
    float s = 0.f;
#pragma unroll
    for (int nt = 0; nt < 4; nt++) s += acc[nt][r];
#pragma unroll
    for (int o = 8; o > 0; o >>= 1) s += __shfl_xor(s, o);
    sum[r] = s;
  }
  if (lr == 0) {
#pragma unroll
    for (int r = 0; r < 4; r++) pred[wid][lh * 4 + r] = sum[r];
  }
  __syncthreads();
  float mu[4];
#pragma unroll
  for (int r = 0; r < 4; r++)
    mu[r] = (pred[0][lh * 4 + r] + pred[1][lh * 4 + r] + pred[2][lh * 4 + r] +
             pred[3][lh * 4 + r]) *
            (1.f / 256.f);
  float qs[4];
#pragma unroll
  for (int r = 0; r < 4; r++) {
    float q = 0.f;
#pragma unroll
    for (int nt = 0; nt < 4; nt++) {
      float d = acc[nt][r] - mu[r];
      q += d * d;
    }
#pragma unroll
    for (int o = 8; o > 0; o >>= 1) q += __shfl_xor(q, o);
    qs[r] = q;
  }
  if (lr == 0) {
#pragma unroll
    for (int r = 0; r < 4; r++) qred[wid][lh * 4 + r] = qs[r];
  }
  __syncthreads();
  float rstd[4];
#pragma unroll
  for (int r = 0; r < 4; r++)
    rstd[r] = rsqrtf((qred[0][lh * 4 + r] + qred[1][lh * 4 + r] +
                      qred[2][lh * 4 + r] + qred[3][lh * 4 + r]) *
                         (1.f / 256.f) +
                     EPSf);
  float oarr[4][4];
#pragma unroll
  for (int nt = 0; nt < 4; nt++) {
    int col = wid * 64 + nt * 16 + lr;
    float gw = g[col], bw = bta[col];
#pragma unroll
    for (int r = 0; r < 4; r++) {
      int row = m0 + rowl + r;
      size_t idx = (size_t)row * 256 + col;
      float o = (acc[nt][r] - mu[r]) * rstd[r] * gw + bw;
      x[idx] = o;
      xb[idx] = f2bf(o);
      if (WRITEQ) {
        size_t pc = idx - (row >= Ntok ? (size_t)Ntok * 256 : 0);
        qb[idx] = f2bf(o + bf2f(peb[pc]));
      }
      if (TOKOUT) oarr[nt][r] = o;
    }
  }
  if constexpr (TOKOUT) {
    __shared__ float tout[16][129];
    int bb = (m0 >= Ntok) ? 1 : 0;
    int n = m0 - bb * Ntok;
    float* outp;
    int osize, ostart;
    if (n < 4096) { outp = o3; osize = 4096; ostart = 0; }
    else if (n < 5120) { outp = o4; osize = 1024; ostart = 4096; }
    else { outp = o5; osize = 256; ostart = 5120; }
    int sp0 = n - ostart;
#pragma unroll
    for (int hh = 0; hh < 2; hh++) {
      __syncthreads();
      if ((wid >> 1) == hh) {
#pragma unroll
        for (int nt = 0; nt < 4; nt++) {
          int cl = (wid & 1) * 64 + nt * 16 + lr;
#pragma unroll
          for (int r = 0; r < 4; r++) tout[rowl + r][cl] = oarr[nt][r];
        }
      }
      __syncthreads();
      int cl = tid & 127, rh = tid >> 7;
      float* dst =
          outp + ((size_t)(bb * 256 + hh * 128 + cl)) * osize + sp0 + rh * 8;
#pragma unroll
      for (int i = 0; i < 8; i += 4) {
        float4 v4 = {tout[rh * 8 + i + 0][cl], tout[rh * 8 + i + 1][cl],
                     tout[rh * 8 + i + 2][cl], tout[rh * 8 + i + 3][cl]};
        *reinterpret_cast<float4*>(&dst[i]) = v4;
      }
    }
  }
}

// =================================================================
// FUSED: msda sampling + out-proj GEMM (K=256) + residual + LN1.
// grid 672, BM=16 rows. attn tile built in LDS (never hits HBM).
// =================================================================
__global__ __launch_bounds__(256) void msda_out_ln(
    const unsigned short* __restrict__ value, const float* __restrict__ off,
    const float* __restrict__ awl, const unsigned short* __restrict__ Wb,
    const float* __restrict__ bias, const float* __restrict__ g,
    const float* __restrict__ bta, float* __restrict__ x,
    unsigned short* __restrict__ xb) {
  __shared__ unsigned short Ws[256 * 64];      // 32KB; first 12288 = rec alias
  __shared__ unsigned short atile[4][16 * 64]; // 8KB
  __shared__ float pred[4][16];
  __shared__ float qred[4][16];
  const int tid = threadIdx.x;
  const int swz = (blockIdx.x & 7) * 84 + (blockIdx.x >> 3);  // grid 672
  const int m0 = swz * 16;
  const int wid = tid >> 6, lane = tid & 63;
  const int lr = lane & 15, lh = lane >> 4;
  const int r8 = tid >> 3, g8 = tid & 7;

  // W prologue loads (k=0) issued before msda work
  uint4 rw[8];
#pragma unroll
  for (int i = 0; i < 8; i++)
    rw[i] = *reinterpret_cast<const uint4*>(
        &Wb[(size_t)(r8 + i * 32) * 256 + g8 * 8]);

  // ---- phase 1: records for 128 groups (16 rows x 8 heads) ----
  unsigned short* rec = Ws;  // [128][12][8]: 4 ushort spat + 4 bf16 weight
  if (tid < 128) {
    int row = m0 + (tid >> 3);
    int h = tid & 7;
    int n = row % Ntok;
    int li0 = (n < 4096) ? 0 : ((n < 5120) ? 1 : 2);
    int start0 = (li0 == 0) ? 0 : ((li0 == 1) ? 4096 : 5120);
    int shift = 6 - li0;
    int Wn = 1 << shift;
    int sp = n - start0;
    int iy = sp >> shift;
    int ix = sp & (Wn - 1);
    float refx = (ix + 0.5f) / (float)Wn;
    float refy = (iy + 0.5f) / (float)Wn;
    const float* ap = awl + (size_t)row * 96 + h * 12;
    float lg[12];
    float mx = -1e30f;
#pragma unroll
    for (int j = 0; j < 12; j++) { lg[j] = ap[j]; mx = fmaxf(mx, lg[j]); }
    float ssum = 0.f;
#pragma unroll
    for (int j = 0; j < 12; j++) { lg[j] = expf(lg[j] - mx); ssum += lg[j]; }
    const float* op = off + (size_t)row * 192 + h * 24;
#pragma unroll
    for (int p = 0; p < 12; p++) {
      int li = p >> 2;
      int HWl = 64 >> li;
      float w = lg[p] / ssum;
      float ox = op[p * 2 + 0];
      float oy = op[p * 2 + 1];
      float lx = refx + ox / (float)HWl;
      float ly = refy + oy / (float)HWl;
      float fx = lx * (float)HWl - 0.5f;
      float fy = ly * (float)HWl - 0.5f;
      float x0f = floorf(fx), y0f = floorf(fy);
      float wx = fx - x0f, wy = fy - y0f;
      int ix0 = (int)x0f, iy0 = (int)y0f;
      unsigned short sp4[4], w4[4];
#pragma unroll
      for (int cr = 0; cr < 4; cr++) {
        int cx = ix0 + (cr & 1);
        int cy = iy0 + (cr >> 1);
        bool valid = (cx >= 0) & (cx < HWl) & (cy >= 0) & (cy < HWl);
        float wc = ((cr & 1) ? wx : 1.f - wx) * ((cr >> 1) ? wy : 1.f - wy);
        int cxc = min(max(cx, 0), HWl - 1);
        int cyc = min(max(cy, 0), HWl - 1);
        sp4[cr] = (unsigned short)(cyc * HWl + cxc);
        w4[cr] = f2bf(valid ? (w * wc) : 0.f);
      }
      *reinterpret_cast<uint2*>(&rec[(tid * 12 + p) * 8]) =
          *reinterpret_cast<const uint2*>(sp4);
      *reinterpret_cast<uint2*>(&rec[(tid * 12 + p) * 8 + 4]) =
          *reinterpret_cast<const uint2*>(w4);
    }
  }
  __syncthreads();
  // ---- phase 2: gather -> atile (bf16, swizzled), uint4-vectorized ----
  {
    int gq = tid >> 1;       // group 0..127
    int half = tid & 1;      // which 16-channel half of the head's 32
    int rr = gq >> 3;        // local row 0..15
    int row = m0 + rr;
    int h = gq & 7;
    int b = (row >= Ntok) ? 1 : 0;
    int coff = h * 32 + half * 16;
    int base0 = (b * Ntok + 0) * 256 + coff;
    int base1 = (b * Ntok + 4096) * 256 + coff;
    int base2 = (b * Ntok + 5120) * 256 + coff;
    float acc[16];
#pragma unroll
    for (int j = 0; j < 16; j++) acc[j] = 0.f;
    const unsigned short* rp = rec + gq * 96;
#pragma unroll
    for (int p = 0; p < 12; p++) {
      int li = p >> 2;
      int base = (li == 0) ? base0 : ((li == 1) ? base1 : base2);
      unsigned short sp4[4], w4[4];
      *reinterpret_cast<uint2*>(sp4) =
          *reinterpret_cast<const uint2*>(&rp[p * 8]);
      *reinterpret_cast<uint2*>(w4) =
          *reinterpret_cast<const uint2*>(&rp[p * 8 + 4]);
#pragma unroll
      for (int cr = 0; cr < 4; cr++) {
        float w = bf2f(w4[cr]);
        const unsigned short* vsrc = value + base + (int)sp4[cr] * 256;
        uint4 va = *reinterpret_cast<const uint4*>(vsrc);
        uint4 vb4 = *reinterpret_cast<const uint4*>(vsrc + 8);
        unsigned uu[8] = {va.x, va.y, va.z, va.w, vb4.x, vb4.y, vb4.z, vb4.w};
#pragma unroll
        for (int j = 0; j < 8; j++) {
          acc[j * 2 + 0] += w * bf2f((unsigned short)(uu[j] & 0xffff));
          acc[j * 2 + 1] += w * bf2f((unsigned short)(uu[j] >> 16));
        }
      }
    }
#pragma unroll
    for (int j = 0; j < 8; j++) {
      int c0 = coff + j * 2;
      int kc = c0 >> 6;
      int cc = c0 & 63;
      int ggr = cc >> 3, el = cc & 7;
      unsigned outw =
          (unsigned)f2bf(acc[j * 2]) | ((unsigned)f2bf(acc[j * 2 + 1]) << 16);
      *reinterpret_cast<unsigned*>(
          &atile[kc][rr * 64 + ((ggr ^ (rr & 7)) * 8) + el]) = outw;
    }
  }
  __syncthreads();  // rec dead; Ws now usable for W tiles

  // ---- phase 3: K=256 GEMM from atile/Ws + LN epilogue ----
  f32x4 acc[4];
#pragma unroll
  for (int i = 0; i < 4; i++) acc[i] = f32x4{0.f, 0.f, 0.f, 0.f};
  for (int k0 = 0; k0 < 256; k0 += 64) {
    if (k0) __syncthreads();
#pragma unroll
    for (int i = 0; i < 8; i++) store_chunk_bf(Ws, r8 + i * 32, g8, rw[i]);
    __syncthreads();
    int kn = k0 + 64;
    if (kn < 256) {
#pragma unroll
      for (int i = 0; i < 8; i++)
        rw[i] = *reinterpret_cast<const uint4*>(
            &Wb[(size_t)(r8 + i * 32) * 256 + kn + g8 * 8]);
    }
    bf16x8 af[2];
    {
      int r = lr;
#pragma unroll
      for (int s = 0; s < 2; s++) {
        int gg2 = s * 4 + lh;
        af[s] = *reinterpret_cast<const bf16x8*>(
            &atile[k0 >> 6][r * 64 + (gg2 ^ (r & 7)) * 8]);
      }
    }
#pragma unroll
    for (int nt = 0; nt < 4; nt++) {
      int r = wid * 64 + nt * 16 + lr;
      bf16x8 b0 =
          *reinterpret_cast<const bf16x8*>(&Ws[r * 64 + (lh ^ (r & 7)) * 8]);
      bf16x8 b1 = *reinterpret_cast<const bf16x8*>(
          &Ws[r * 64 + ((4 + lh) ^ (r & 7)) * 8]);
      acc[nt] =
          __builtin_amdgcn_mfma_f32_16x16x32_bf16(af[0], b0, acc[nt], 0, 0, 0);
      acc[nt] =
          __builtin_amdgcn_mfma_f32_16x16x32_bf16(af[1], b1, acc[nt], 0, 0, 0);
    }
  }

  const int rowl = lh * 4;
#pragma unroll
  for (int nt = 0; nt < 4; nt++) {
    int col = wid * 64 + nt * 16 + lr;
    float bs = bias[col];
#pragma unroll
    for (int r = 0; r < 4; r++)
      acc[nt][r] += bs + x[(size_t)(m0 + rowl + r) * 256 + col];
  }
  float sum[4];
#pragma unroll
  for (int r = 0; r < 4; r++) {
    float s = 0.f;
#pragma unroll
    for (int nt = 0; nt < 4; nt++) s += acc[nt][r];
#pragma unroll
    for (int o = 8; o > 0; o >>= 1) s += __shfl_xor(s, o);
    sum[r] = s;
  }
  if (lr == 0) {
#pragma unroll
    for (int r = 0; r < 4; r++) pred[wid][lh * 4 + r] = sum[r];
  }
  __syncthreads();
  float mu[4];
#pragma unroll
  for (int r = 0; r < 4; r++)
    mu[r] = (pred[0][lh * 4 + r] + pred[1][lh * 4 + r] + pred[2][lh * 4 + r] +
             pred[3][lh * 4 + r]) *
            (1.f / 256.f);
  float qs[4];
#pragma unroll
  for (int r = 0; r < 4; r++) {
    float q = 0.f;
#pragma unroll
    for (int nt = 0; nt < 4; nt++) {
      float d = acc[nt][r] - mu[r];
      q += d * d;
    }
#pragma unroll
    for (int o = 8; o > 0; o >>= 1) q += __shfl_xor(q, o);
    qs[r] = q;
  }
  if (lr == 0) {
#pragma unroll
    for (int r = 0; r < 4; r++) qred[wid][lh * 4 + r] = qs[r];
  }
  __syncthreads();
  float rstd[4];
#pragma unroll
  for (int r = 0; r < 4; r++)
    rstd[r] = rsqrtf((qred[0][lh * 4 + r] + qred[1][lh * 4 + r] +
                      qred[2][lh * 4 + r] + qred[3][lh * 4 + r]) *
                         (1.f / 256.f) +
                     EPSf);
#pragma unroll
  for (int nt = 0; nt < 4; nt++) {
    int col = wid * 64 + nt * 16 + lr;
    float gw = g[col], bw = bta[col];
#pragma unroll
    for (int r = 0; r < 4; r++) {
      int row = m0 + rowl + r;
      size_t idx = (size_t)row * 256 + col;
      float o = (acc[nt][r] - mu[r]) * rstd[r] * gw + bw;
      x[idx] = o;
      xb[idx] = f2bf(o);
    }
  }
}

// -------- fused head GEMMs, BM=32: val (0..671) + off/aw (672..1679) --------
__global__ __launch_bounds__(256) void gemm_head(
    const unsigned short* __restrict__ xb, const unsigned short* __restrict__ qb,
    const unsigned short* __restrict__ wv, const unsigned short* __restrict__ wo,
    const float* __restrict__ valB, const float* __restrict__ offB,
    const float* __restrict__ awB, unsigned short* __restrict__ valO,
    float* __restrict__ offO, float* __restrict__ awO) {
  __shared__ unsigned short As[32 * 64];
  __shared__ unsigned short Ws[128 * 64];
  const int tid = threadIdx.x;
  const int swz = (blockIdx.x & 7) * 210 + (blockIdx.x >> 3);  // grid 1680
  const bool isval = swz < 672;
  const unsigned short* A;
  const unsigned short* W;
  int m0, n0, Nn;
  if (isval) {
    A = xb; W = wv; Nn = 256;
    m0 = (swz >> 1) * 32; n0 = (swz & 1) * 128;
  } else {
    int s = swz - 672;
    A = qb; W = wo; Nn = 288;
    m0 = (s / 3) * 32; n0 = (s % 3) * 128;
  }
  const int wid = tid >> 6, lane = tid & 63;
  const int wm = wid >> 1, wn = wid & 1;
  const int lr = lane & 15, lh = lane >> 4;
  const int r8 = tid >> 3, g8 = tid & 7;
  f32x4 acc[4];
#pragma unroll
  for (int j = 0; j < 4; j++) acc[j] = f32x4{0.f, 0.f, 0.f, 0.f};

  uint4 ra, rw[4];
  const uint4 z4 = uint4{0, 0, 0, 0};
  ra = *reinterpret_cast<const uint4*>(&A[(size_t)(m0 + r8) * 256 + g8 * 8]);
#pragma unroll
  for (int i = 0; i < 4; i++) {
    int n = n0 + r8 + i * 32;
    rw[i] = (n < Nn) ? *reinterpret_cast<const uint4*>(
                           &W[(size_t)n * 256 + g8 * 8])
                     : z4;
  }

  for (int k0 = 0; k0 < 256; k0 += 64) {
    if (k0) __syncthreads();
    store_chunk_bf(As, r8, g8, ra);
#pragma unroll
    for (int i = 0; i < 4; i++) store_chunk_bf(Ws, r8 + i * 32, g8, rw[i]);
    __syncthreads();
    int kn = k0 + 64;
    if (kn < 256) {
      ra = *reinterpret_cast<const uint4*>(
          &A[(size_t)(m0 + r8) * 256 + kn + g8 * 8]);
#pragma unroll
      for (int i = 0; i < 4; i++) {
        int n = n0 + r8 + i * 32;
        rw[i] = (n < Nn) ? *reinterpret_cast<const uint4*>(
                               &W[(size_t)n * 256 + kn + g8 * 8])
                         : z4;
      }
    }
    bf16x8 af[2];
    {
      int r = wm * 16 + lr;
#pragma unroll
      for (int s = 0; s < 2; s++) {
        int gg2 = s * 4 + lh;
        af[s] =
            *reinterpret_cast<const bf16x8*>(&As[r * 64 + (gg2 ^ (r & 7)) * 8]);
      }
    }
#pragma unroll
    for (int nj = 0; nj < 4; nj++) {
      int r = wn * 64 + nj * 16 + lr;
      bf16x8 b0 =
          *reinterpret_cast<const bf16x8*>(&Ws[r * 64 + (lh ^ (r & 7)) * 8]);
      bf16x8 b1 = *reinterpret_cast<const bf16x8*>(
          &Ws[r * 64 + ((4 + lh) ^ (r & 7)) * 8]);
      acc[nj] =
          __builtin_amdgcn_mfma_f32_16x16x32_bf16(af[0], b0, acc[nj], 0, 0, 0);
      acc[nj] =
          __builtin_amdgcn_mfma_f32_16x16x32_bf16(af[1], b1, acc[nj], 0, 0, 0);
    }
  }
  const int row0 = m0 + wm * 16 + lh * 4;
#pragma unroll
  for (int nj = 0; nj < 4; nj++) {
    int col = n0 + wn * 64 + nj * 16 + lr;
    if (isval) {
      float b = valB[col];
#pragma unroll
      for (int r = 0; r < 4; r++)
        valO[(size_t)(row0 + r) * 256 + col] = f2bf(acc[nj][r] + b);
    } else {
      if (col >= 288) continue;
      float b = (col < 192) ? offB[col] : awB[col - 192];
#pragma unroll
      for (int r = 0; r < 4; r++) {
        float v = acc[nj][r] + b;
        if (col < 192)
          offO[(size_t)(row0 + r) * 192 + col] = v;
        else
          awO[(size_t)(row0 + r) * 96 + col - 192] = v;
      }
    }
  }
}

// ------------- implicit-GEMM 3x3 conv, BM=128 x BN=256 (full N), grid 256 -------------
// Per-wave tile 64x128: LDS reads/MFMA = 0.375 (vs 0.5 at BN=128).
// + fused GN partial sums. Conv outputs bit-identical to previous versions.
__global__ __launch_bounds__(256) void conv3x3_mfma(
    const unsigned short* __restrict__ T, const unsigned short* __restrict__ Wt,
    const float* __restrict__ bias, unsigned short* __restrict__ out,
    float* __restrict__ gnpart) {
  __shared__ unsigned short As[128 * 64];
  __shared__ unsigned short Ws[256 * 64];
  __shared__ float gs[2][2][8][2];
  __shared__ float gq2[2][2][8][2];
  const int tid = threadIdx.x;
  const int swz = (blockIdx.x & 7) * 32 + (blockIdx.x >> 3);  // grid 256
  const int m0 = swz * 128;  // n0 = 0 (full N)
  const int b = m0 >> 14;
  const int p0 = m0 & 16383;
  const int y = p0 >> 7;
  const int wid = tid >> 6, lane = tid & 63;
  const int wm = wid >> 1, wn = wid & 1;
  const int lr = lane & 15, lh = lane >> 4;
  const int r8 = tid >> 3, g8 = tid & 7;
  f32x4 acc[4][8];
#pragma unroll
  for (int i = 0; i < 4; i++)
#pragma unroll
    for (int j = 0; j < 8; j++) acc[i][j] = f32x4{0.f, 0.f, 0.f, 0.f};

  uint4 ra[4], rw[8];
  auto loadA = [&](int kc, uint4* r) {
    int tap = kc >> 2;
    int cb = (kc & 3) * 64;
    int dy = tap / 3 - 1, dx = tap % 3 - 1;
    int yy = y + dy;
#pragma unroll
    for (int i = 0; i < 4; i++) {
      int row = r8 + i * 32;
      int xx = row + dx;
      uint4 v = uint4{0, 0, 0, 0};
      if (yy >= 0 && yy < 128 && xx >= 0 && xx < 128)
        v = *reinterpret_cast<const uint4*>(
            &T[((size_t)(b * 16384 + yy * 128 + xx)) * 256 + cb + g8 * 8]);
      r[i] = v;
    }
  };
  auto loadW = [&](int kc, uint4* r) {
#pragma unroll
    for (int i = 0; i < 8; i++)
      r[i] = *reinterpret_cast<const uint4*>(
          &Wt[(size_t)(r8 + i * 32) * 2304 + kc * 64 + g8 * 8]);
  };
  loadA(0, ra);
  loadW(0, rw);

  for (int kc = 0; kc < 36; kc++) {
    if (kc) __syncthreads();
#pragma unroll
    for (int i = 0; i < 4; i++) store_chunk_bf(As, r8 + i * 32, g8, ra[i]);
#pragma unroll
    for (int i = 0; i < 8; i++) store_chunk_bf(Ws, r8 + i * 32, g8, rw[i]);
    __syncthreads();
    if (kc + 1 < 36) {
      loadA(kc + 1, ra);
      loadW(kc + 1, rw);
    }
    bf16x8 af[4][2], bfr[8][2];
#pragma unroll
    for (int mi = 0; mi < 4; mi++) {
      int r = wm * 64 + mi * 16 + lr;
#pragma unroll
      for (int s = 0; s < 2; s++) {
        int g = s * 4 + lh;
        af[mi][s] =
            *reinterpret_cast<const bf16x8*>(&As[r * 64 + (g ^ (r & 7)) * 8]);
      }
    }
#pragma unroll
    for (int nj = 0; nj < 8; nj++) {
      int r = wn * 128 + nj * 16 + lr;
#pragma unroll
      for (int s = 0; s < 2; s++) {
        int g = s * 4 + lh;
        bfr[nj][s] =
            *reinterpret_cast<const bf16x8*>(&Ws[r * 64 + (g ^ (r & 7)) * 8]);
      }
    }
#pragma unroll
    for (int mi = 0; mi < 4; mi++)
#pragma unroll
      for (int nj = 0; nj < 8; nj++) {
        acc[mi][nj] = __builtin_amdgcn_mfma_f32_16x16x32_bf16(
            af[mi][0], bfr[nj][0], acc[mi][nj], 0, 0, 0);
        acc[mi][nj] = __builtin_amdgcn_mfma_f32_16x16x32_bf16(
            af[mi][1], bfr[nj][1], acc[mi][nj], 0, 0, 0);
      }
  }
  // epilogue: write bf16 output and accumulate GN partials per column-group
  float gsumv[8] = {0.f, 0.f, 0.f, 0.f, 0.f, 0.f, 0.f, 0.f};
  float gsqv[8] = {0.f, 0.f, 0.f, 0.f, 0.f, 0.f, 0.f, 0.f};
#pragma unroll
  for (int mi = 0; mi < 4; mi++) {
    int row = m0 + wm * 64 + mi * 16 + lh * 4;
#pragma unroll
    for (int nj = 0; nj < 8; nj++) {
      int col = wn * 128 + nj * 16 + lr;
      float bv = bias[col];
#pragma unroll
      for (int r = 0; r < 4; r++) {
        unsigned short ob = f2bf(acc[mi][nj][r] + bv);
        out[(size_t)(row + r) * 256 + col] = ob;
        float vv = bf2f(ob);
        gsumv[nj] += vv;
        gsqv[nj] += vv * vv;
      }
    }
  }
  // reduce over lanes sharing (lr>>3): xor masks 1,2,4 (lr low) + 16,32 (lh)
#pragma unroll
  for (int nj = 0; nj < 8; nj++) {
    float s = gsumv[nj], q = gsqv[nj];
    s += __shfl_xor(s, 1);  q += __shfl_xor(q, 1);
    s += __shfl_xor(s, 2);  q += __shfl_xor(q, 2);
    s += __shfl_xor(s, 4);  q += __shfl_xor(q, 4);
    s += __shfl_xor(s, 16); q += __shfl_xor(q, 16);
    s += __shfl_xor(s, 32); q += __shfl_xor(q, 32);
    gsumv[nj] = s;
    gsqv[nj] = q;
  }
  if ((lane & 7) == 0 && lh == 0) {
    int half = (lane >> 3) & 1;
#pragma unroll
    for (int nj = 0; nj < 8; nj++) {
      gs[wm][wn][nj][half] = gsumv[nj];
      gq2[wm][wn][nj][half] = gsqv[nj];
    }
  }
  __syncthreads();
  if (tid < 32) {
    int wn2 = tid >> 4, r = tid & 15, nj = r >> 1, half = r & 1;
    float s = gs[0][wn2][nj][half] + gs[1][wn2][nj][half];
    float q = gq2[0][wn2][nj][half] + gq2[1][wn2][nj][half];
    int g = wn2 * 16 + nj * 2 + half;  // group in [0,32)
    int t = swz;                       // pixel tile incl. batch, [0,256)
    gnpart[((size_t)t * 32 + g) * 2 + 0] = s;
    gnpart[((size_t)t * 32 + g) * 2 + 1] = q;
  }
}

// ------------- TN GEMM (1x1 lateral conv) + fused bilinear upsample-add -------------
__global__ __launch_bounds__(256) void gemm_tn_mfma(
    const float* __restrict__ A, const unsigned short* __restrict__ Wb,
    const float* __restrict__ bias, const float* __restrict__ x,
    unsigned short* __restrict__ out) {
  __shared__ unsigned short As[64 * 64];
  __shared__ unsigned short Ws[128 * 64];
  const int tid = threadIdx.x;
  const int nwg = gridDim.x;  // 1024
  const int swz = (blockIdx.x & 7) * (nwg >> 3) + (blockIdx.x >> 3);
  const int m0 = (swz >> 1) * 64, n0 = (swz & 1) * 128;
  const int b = m0 >> 14;
  const int p0 = m0 & 16383;
  const int wid = tid >> 6, lane = tid & 63;
  const int wm = wid >> 1, wn = wid & 1;
  const int lr = lane & 15, lh = lane >> 4;
  const int r8 = tid >> 3, g8 = tid & 7;
  const int arow = tid & 63, agb = tid >> 6;
  f32x4 acc[2][4];
#pragma unroll
  for (int i = 0; i < 2; i++)
#pragma unroll
    for (int j = 0; j < 4; j++) acc[i][j] = f32x4{0.f, 0.f, 0.f, 0.f};

  float va[16];
  uint4 rw[4];
  auto loadA = [&](int k0, float* v) {
#pragma unroll
    for (int i = 0; i < 2; i++) {
      int g = agb + i * 4;
#pragma unroll
      for (int j = 0; j < 8; j++)
        v[i * 8 + j] =
            A[(size_t)(b * 256 + k0 + g * 8 + j) * 16384 + p0 + arow];
    }
  };
  auto loadW = [&](int k0, uint4* r) {
#pragma unroll
    for (int i = 0; i < 4; i++)
      r[i] = *reinterpret_cast<const uint4*>(
          &Wb[(size_t)(n0 + r8 + i * 32) * 256 + k0 + g8 * 8]);
  };
  loadA(0, va);
  loadW(0, rw);

  for (int k0 = 0; k0 < 256; k0 += 64) {
    if (k0) __syncthreads();
#pragma unroll
    for (int i = 0; i < 2; i++)
      store_chunk_f32(As, arow, agb + i * 4, &va[i * 8]);
#pragma unroll
    for (int i = 0; i < 4; i++) store_chunk_bf(Ws, r8 + i * 32, g8, rw[i]);
    __syncthreads();
    int kn = k0 + 64;
    if (kn < 256) {
      loadA(kn, va);
      loadW(kn, rw);
    }
    bf16x8 af[2][2], bfr[4][2];
#pragma unroll
    for (int mi = 0; mi < 2; mi++) {
      int r = wm * 32 + mi * 16 + lr;
#pragma unroll
      for (int s = 0; s < 2; s++) {
        int g = s * 4 + lh;
        af[mi][s] =
            *reinterpret_cast<const bf16x8*>(&As[r * 64 + (g ^ (r & 7)) * 8]);
      }
    }
#pragma unroll
    for (int nj = 0; nj < 4; nj++) {
      int r = wn * 64 + nj * 16 + lr;
#pragma unroll
      for (int s = 0; s < 2; s++) {
        int g = s * 4 + lh;
        bfr[nj][s] =
            *reinterpret_cast<const bf16x8*>(&Ws[r * 64 + (g ^ (r & 7)) * 8]);
      }
    }
#pragma unroll
    for (int mi = 0; mi < 2; mi++)
#pragma unroll
      for (int nj = 0; nj < 4; nj++) {
        acc[mi][nj] = __builtin_amdgcn_mfma_f32_16x16x32_bf16(
            af[mi][0], bfr[nj][0], acc[mi][nj], 0, 0, 0);
        acc[mi][nj] = __builtin_amdgcn_mfma_f32_16x16x32_bf16(
            af[mi][1], bfr[nj][1], acc[mi][nj], 0, 0, 0);
      }
  }
  const float* xbse = x + (size_t)b * Ntok * 256;
#pragma unroll
  for (int mi = 0; mi < 2; mi++) {
    int row0 = m0 + wm * 32 + mi * 16 + lh * 4;
#pragma unroll
    for (int r = 0; r < 4; r++) {
      int p = (row0 + r) & 16383;
      int Y = p >> 7, X = p & 127;
      float yc = Y * 0.5f - 0.25f;
      float y0f = floorf(yc);
      float wy = yc - y0f;
      int y0 = (int)y0f;
      int y0c = min(max(y0, 0), 63), y1c = min(max(y0 + 1, 0), 63);
      float xc = X * 0.5f - 0.25f;
      float x0f = floorf(xc);
      float wx = xc - x0f;
      int xq0 = (int)x0f;
      int x0c = min(max(xq0, 0), 63), x1c = min(max(xq0 + 1, 0), 63);
      const float* r00 = xbse + (size_t)(y0c * 64 + x0c) * 256;
      const float* r01 = xbse + (size_t)(y0c * 64 + x1c) * 256;
      const float* r10 = xbse + (size_t)(y1c * 64 + x0c) * 256;
      const float* r11 = xbse + (size_t)(y1c * 64 + x1c) * 256;
#pragma unroll
      for (int nj = 0; nj < 4; nj++) {
        int col = n0 + wn * 64 + nj * 16 + lr;
        float up = (1.f - wy) * ((1.f - wx) * r00[col] + wx * r01[col]) +
                   wy * ((1.f - wx) * r10[col] + wx * r11[col]);
        out[(size_t)(row0 + r) * 256 + col] =
            f2bf(acc[mi][nj][r] + bias[col] + up);
      }
    }
  }
}

// ---------------- GN final: parallel reduce 128 tile-partials per (b,g) ----------------
// grid 64 blocks (one per b*32+g), 128 threads: thread t loads tile t's partial.
__global__ __launch_bounds__(128) void gn_final(const float* __restrict__ part,
                                                float* __restrict__ stats) {
  __shared__ float rs[128], rq[128];
  int bg = blockIdx.x;  // b*32+g
  int b = bg >> 5, g = bg & 31;
  int tid = threadIdx.x;
  int t = b * 128 + tid;
  rs[tid] = part[((size_t)t * 32 + g) * 2 + 0];
  rq[tid] = part[((size_t)t * 32 + g) * 2 + 1];
  __syncthreads();
  for (int st = 64; st > 0; st >>= 1) {
    if (tid < st) {
      rs[tid] += rs[tid + st];
      rq[tid] += rq[tid + st];
    }
    __syncthreads();
  }
  if (tid == 0) {
    float mu = rs[0] * (1.f / 131072.f);
    float var = rq[0] * (1.f / 131072.f) - mu * mu;
    stats[bg * 2 + 0] = mu;
    stats[bg * 2 + 1] = rsqrtf(var + EPSf);
  }
}

// ---------------- GN apply + GELU + transpose to NCHW (bf16 input) ----------------
__global__ void gn_apply(const unsigned short* __restrict__ s,
                         const float* __restrict__ stats,
                         const float* __restrict__ gg,
                         const float* __restrict__ gb,
                         float* __restrict__ out) {
  __shared__ float tile[32][33];
  int p0 = blockIdx.x * 32, c0 = blockIdx.y * 32, b = blockIdx.z;
  int tx = threadIdx.x, tyy = threadIdx.y;
  int c = c0 + tx;
  float mu = stats[(b * 32 + (c >> 3)) * 2 + 0];
  float rstd = stats[(b * 32 + (c >> 3)) * 2 + 1];
  float gw = gg[c], bw = gb[c];
  for (int i = tyy; i < 32; i += 8) {
    float v = bf2f(s[((size_t)(b * 16384 + p0 + i)) * 256 + c]);
    v = (v - mu) * rstd * gw + bw;
    v = 0.5f * v * (1.f + erff(v * 0.70710678118654752f));
    tile[i][tx] = v;
  }
  __syncthreads();
  for (int i = tyy; i < 32; i += 8)
    out[((size_t)(b * 256 + c0 + i)) * 16384 + p0 + tx] = tile[tx][i];
}

// ---------------- launcher ----------------
extern "C" void kernel_launch(void* const* d_in, const int* in_sizes, int n_in,
                              void* d_out, int out_size, void* d_ws,
                              size_t ws_size, hipStream_t stream) {
  (void)in_sizes; (void)n_in; (void)out_size; (void)ws_size;
  const float* res2  = (const float*)d_in[0];
  const float* res3  = (const float*)d_in[1];
  const float* res4  = (const float*)d_in[2];
  const float* res5  = (const float*)d_in[3];
  const float* lemb  = (const float*)d_in[4];
  const float* off_W = (const float*)d_in[5];
  const float* off_b = (const float*)d_in[6];
  const float* aw_W  = (const float*)d_in[7];
  const float* aw_b  = (const float*)d_in[8];
  const float* val_W = (const float*)d_in[9];
  const float* val_b = (const float*)d_in[10];
  const float* out_W = (const float*)d_in[11];
  const float* out_b = (const float*)d_in[12];
  const float* ln1_g = (const float*)d_in[13];
  const float* ln1_b = (const float*)d_in[14];
  const float* fc1_W = (const float*)d_in[15];
  const float* fc1_b = (const float*)d_in[16];
  const float* fc2_W = (const float*)d_in[17];
  const float* fc2_b = (const float*)d_in[18];
  const float* ln2_g = (const float*)d_in[19];
  const float* ln2_b = (const float*)d_in[20];
  const float* lat_W = (const float*)d_in[21];
  const float* lat_b = (const float*)d_in[22];
  const float* sm_W  = (const float*)d_in[23];
  const float* sm_b  = (const float*)d_in[24];
  const float* gn_g  = (const float*)d_in[25];
  const float* gn_b  = (const float*)d_in[26];

  float* ws = (float*)d_ws;
  // layout (float units); bf16 buffers take count/2 floats
  float*          x      = ws;                               // (2752512)
  unsigned short* xb     = (unsigned short*)(ws + 2752512);  // (1376256 bf16)
  unsigned short* peb    = (unsigned short*)(ws + 4128768);  // (688128 bf16)
  unsigned short* qb     = (unsigned short*)(ws + 4816896);  // (1376256 bf16)
  unsigned short* valueb = (unsigned short*)(ws + 6193152);  // (1376256 bf16)
  float*          offb   = ws + 7569408;                     // (2064384 f)
  float*          awl    = ws + 9633792;                     // (1032192 f)
  unsigned short* hb     = (unsigned short*)(ws + 14794752); // (5505024 bf16)
  unsigned short* tbuf   = hb;  // conv input aliases hb (dead after layers)
  unsigned short* wtbuf  = (unsigned short*)(ws + 20299776); // 589824 bf16 -> ends 20594688f
  unsigned short* wbf    = (unsigned short*)(ws + 20596864); // 6*WL+65536 bf16
  unsigned short* wlat   = wbf + (size_t)6 * WL;
  unsigned short* sbufb  = (unsigned short*)ws;  // conv out bf16, dead x span
  // gnpart/gnstat alias offb (dead after last layer's msda_out_ln)
  float*          gnpart = ws + 7569408;                     // 16384 floats
  float*          gnstat = ws + 7585792;                     // 128 floats

  float* out_s  = (float*)d_out;
  float* out_o3 = out_s + (size_t)Bn * Cc * HW2;
  float* out_o4 = out_o3 + (size_t)Bn * Cc * 4096;
  float* out_o5 = out_o4 + (size_t)Bn * Cc * 1024;

  const int M = Bn * Ntok;  // 10752

  setup_all<<<7664, 256, 0, stream>>>(res3, res4, res5, lemb, x, xb, qb, peb,
                                      val_W, off_W, aw_W, out_W, fc1_W, fc2_W,
                                      lat_W, sm_W, wbf, wlat, wtbuf);

  for (int l = 0; l < 6; l++) {
    const unsigned short* wl = wbf + (size_t)l * WL;
    gemm_head<<<1680, 256, 0, stream>>>(
        xb, qb, wl + 0, wl + 65536, val_b + l * 256, off_b + l * 192,
        aw_b + l * 96, valueb, offb, awl);
    msda_out_ln<<<672, 256, 0, stream>>>(
        valueb, offb, awl, wl + 139264, out_b + l * 256, ln1_g + l * 256,
        ln1_b + l * 256, x, xb);
    gemm_mfma_b<1, 1><<<1344, 256, 0, stream>>>(
        xb, wl + 204800, fc1_b + l * 1024, hb, M, 1024, 256, 8);
    if (l < 5)
      gemm_ln<1, 0><<<672, 256, 0, stream>>>(
          hb, wl + 466944, fc2_b + l * 256, ln2_g + l * 256, ln2_b + l * 256,
          x, xb, peb, qb, 1024, nullptr, nullptr, nullptr);
    else
      gemm_ln<0, 1><<<672, 256, 0, stream>>>(
          hb, wl + 466944, fc2_b + l * 256, ln2_g + l * 256, ln2_b + l * 256,
          x, xb, peb, qb, 1024, out_o3, out_o4, out_o5);
  }

  // FPN tail: lat-GEMM with fused upsample-add (reads x), then conv+GN-partials
  gemm_tn_mfma<<<1024, 256, 0, stream>>>(res2, wlat, lat_b, x, tbuf);
  conv3x3_mfma<<<256, 256, 0, stream>>>(tbuf, wtbuf, sm_b, sbufb, gnpart);
  gn_final<<<64, 128, 0, stream>>>(gnpart, gnstat);
  gn_apply<<<dim3(512, 8, 2), dim3(32, 8), 0, stream>>>(sbufb, gnstat, gn_g,
                                                        gn_b, out_s);
}

// Round 26
// 621.815 us; speedup vs baseline: 1.0101x; 1.0101x over previous
//
#include <hip/hip_runtime.h>

// ---------------- constants ----------------
namespace {
constexpr int Bn   = 2;
constexpr int Cc   = 256;
constexpr int Ntok = 5376;      // 4096 + 1024 + 256
constexpr int Ffn  = 1024;
constexpr int HW2  = 128 * 128; // res2 spatial
constexpr float EPSf = 1e-5f;
constexpr int WL   = 729088;    // bf16 elems per layer weight block
}

typedef __attribute__((ext_vector_type(8))) short bf16x8;
typedef __attribute__((ext_vector_type(4))) float f32x4;

__device__ inline unsigned short f2bf(float x) {
  unsigned u = __float_as_uint(x);
  return (unsigned short)((u + 0x7fffu + ((u >> 16) & 1u)) >> 16);
}
__device__ inline float bf2f(unsigned short b) {
  return __uint_as_float((unsigned)b << 16);
}

__device__ inline void store_chunk_f32(unsigned short* lds, int row, int g,
                                       const float* v8) {
  int sg = g ^ (row & 7);
  unsigned short tmp[8];
#pragma unroll
  for (int j = 0; j < 8; j++) tmp[j] = f2bf(v8[j]);
  *reinterpret_cast<uint4*>(&lds[row * 64 + sg * 8]) =
      *reinterpret_cast<const uint4*>(tmp);
}
__device__ inline void store_chunk_bf(unsigned short* lds, int row, int g,
                                      uint4 v) {
  int sg = g ^ (row & 7);
  *reinterpret_cast<uint4*>(&lds[row * 64 + sg * 8]) = v;
}

// ---------------- fused setup: flatten+PE (blocks 0..1023) + weight prep ----------------
__global__ __launch_bounds__(256) void setup_all(
    const float* __restrict__ r3, const float* __restrict__ r4,
    const float* __restrict__ r5, const float* __restrict__ lemb,
    float* __restrict__ x, unsigned short* __restrict__ xb,
    unsigned short* __restrict__ qb, unsigned short* __restrict__ peb,
    const float* __restrict__ valW, const float* __restrict__ offW,
    const float* __restrict__ awW, const float* __restrict__ outW,
    const float* __restrict__ fc1W, const float* __restrict__ fc2W,
    const float* __restrict__ latW, const float* __restrict__ smW,
    unsigned short* __restrict__ wbf, unsigned short* __restrict__ wlat,
    unsigned short* __restrict__ wt) {
  int bx = blockIdx.x;
  int tid = threadIdx.x;
  if (bx < 1024) {
    const int NPC = Ntok * Cc;
    for (int i = bx * 256 + tid; i < Bn * NPC; i += 1024 * 256) {
      int c = i & 255;
      int rest = i >> 8;
      int p = rest % Ntok;
      int b = rest / Ntok;
      int li = (p < 4096) ? 0 : ((p < 5120) ? 1 : 2);
      int start = (li == 0) ? 0 : ((li == 1) ? 4096 : 5120);
      int size = (li == 0) ? 4096 : ((li == 1) ? 1024 : 256);
      const float* f = (li == 0) ? r3 : ((li == 1) ? r4 : r5);
      int sp = p - start;
      int shift = 6 - li;
      int W = 64 >> li;
      int iy = sp >> shift;
      int ix = sp & (W - 1);
      int j = c & 63;
      int sel = c >> 6;
      float div = expf(-(float)j * (9.210340371976184f / 64.f));
      float coord = (sel < 2) ? (float)iy : (float)ix;
      float arg = coord * div;
      unsigned short pe16 = f2bf((sel & 1) ? cosf(arg) : sinf(arg));
      float v = f[((size_t)(b * Cc + c)) * size + sp] + lemb[li * Cc + c];
      x[i] = v;
      xb[i] = f2bf(v);
      qb[i] = f2bf(v + bf2f(pe16));
      peb[i - b * NPC] = pe16;
    }
    return;
  }
  int b2 = bx - 1024;
  if (b2 < 4272) {
    int i4 = b2 * 256 + tid;  // < 1093632
    int l = i4 / 182272;
    int e = (i4 - l * 182272) * 4;
    const float* src;
    int off;
    if (e < 65536) { src = valW + (size_t)l * 65536; off = e; }
    else if (e < 139264) {
      int j = e - 65536;
      if (j < 49152) { src = offW + (size_t)l * 49152; off = j; }
      else { src = awW + (size_t)l * 24576; off = j - 49152; }
    } else if (e < 204800) { src = outW + (size_t)l * 65536; off = e - 139264; }
    else if (e < 466944) { src = fc1W + (size_t)l * 262144; off = e - 204800; }
    else { src = fc2W + (size_t)l * 262144; off = e - 466944; }
    float4 v = *reinterpret_cast<const float4*>(&src[off]);
    unsigned short t[4] = {f2bf(v.x), f2bf(v.y), f2bf(v.z), f2bf(v.w)};
    *reinterpret_cast<uint2*>(&wbf[(size_t)l * WL + e]) =
        *reinterpret_cast<const uint2*>(t);
  } else if (b2 < 4336) {
    int e = ((b2 - 4272) * 256 + tid) * 4;  // < 65536
    float4 v = *reinterpret_cast<const float4*>(&latW[e]);
    unsigned short t[4] = {f2bf(v.x), f2bf(v.y), f2bf(v.z), f2bf(v.w)};
    *reinterpret_cast<uint2*>(&wlat[e]) = *reinterpret_cast<const uint2*>(t);
  } else {
    int i = (b2 - 4336) * 256 + tid;  // < 589824
    int o = i / 2304;
    int r = i - o * 2304;
    int tap = r >> 8;
    int c = r & 255;
    wt[i] = f2bf(smW[((size_t)(o * 256 + c)) * 9 + tap]);
  }
}

// =================================================================
// Generic MFMA GEMM: out(M,N) = A(M,K)bf16 @ Wb(N,K)^T bf16 + bias.
// BM=64, BN=128, BK=64, 256 threads = 4 waves (2x2), 16x16x32 mfma.
// =================================================================
template <int ACT, int OBF>
__global__ __launch_bounds__(256) void gemm_mfma_b(
    const unsigned short* __restrict__ A, const unsigned short* __restrict__ Wb,
    const float* __restrict__ bias, void* __restrict__ outp,
    int M, int N, int K, int nbx) {
  __shared__ unsigned short As[64 * 64];
  __shared__ unsigned short Ws[128 * 64];
  const int tid = threadIdx.x;
  const int nwg = gridDim.x;
  const int swz = (blockIdx.x & 7) * (nwg >> 3) + (blockIdx.x >> 3);
  const int m0 = (swz / nbx) * 64, n0 = (swz % nbx) * 128;
  const int wid = tid >> 6, lane = tid & 63;
  const int wm = wid >> 1, wn = wid & 1;
  const int lr = lane & 15, lh = lane >> 4;
  const int r8 = tid >> 3, g8 = tid & 7;
  f32x4 acc[2][4];
#pragma unroll
  for (int i = 0; i < 2; i++)
#pragma unroll
    for (int j = 0; j < 4; j++) acc[i][j] = f32x4{0.f, 0.f, 0.f, 0.f};

  uint4 ra[2], rw[4];
  const uint4 z4 = uint4{0, 0, 0, 0};
#pragma unroll
  for (int i = 0; i < 2; i++)
    ra[i] = *reinterpret_cast<const uint4*>(
        &A[(size_t)(m0 + r8 + i * 32) * K + g8 * 8]);
#pragma unroll
  for (int i = 0; i < 4; i++) {
    int n = n0 + r8 + i * 32;
    rw[i] = (n < N) ? *reinterpret_cast<const uint4*>(
                          &Wb[(size_t)n * K + g8 * 8])
                    : z4;
  }

  for (int k0 = 0; k0 < K; k0 += 64) {
    if (k0) __syncthreads();
#pragma unroll
    for (int i = 0; i < 2; i++) store_chunk_bf(As, r8 + i * 32, g8, ra[i]);
#pragma unroll
    for (int i = 0; i < 4; i++) store_chunk_bf(Ws, r8 + i * 32, g8, rw[i]);
    __syncthreads();
    int kn = k0 + 64;
    if (kn < K) {
#pragma unroll
      for (int i = 0; i < 2; i++)
        ra[i] = *reinterpret_cast<const uint4*>(
            &A[(size_t)(m0 + r8 + i * 32) * K + kn + g8 * 8]);
#pragma unroll
      for (int i = 0; i < 4; i++) {
        int n = n0 + r8 + i * 32;
        rw[i] = (n < N) ? *reinterpret_cast<const uint4*>(
                              &Wb[(size_t)n * K + kn + g8 * 8])
                        : z4;
      }
    }
    bf16x8 af[2][2], bfr[4][2];
#pragma unroll
    for (int mi = 0; mi < 2; mi++) {
      int r = wm * 32 + mi * 16 + lr;
#pragma unroll
      for (int s = 0; s < 2; s++) {
        int g = s * 4 + lh;
        af[mi][s] =
            *reinterpret_cast<const bf16x8*>(&As[r * 64 + (g ^ (r & 7)) * 8]);
      }
    }
#pragma unroll
    for (int nj = 0; nj < 4; nj++) {
      int r = wn * 64 + nj * 16 + lr;
#pragma unroll
      for (int s = 0; s < 2; s++) {
        int g = s * 4 + lh;
        bfr[nj][s] =
            *reinterpret_cast<const bf16x8*>(&Ws[r * 64 + (g ^ (r & 7)) * 8]);
      }
    }
#pragma unroll
    for (int mi = 0; mi < 2; mi++)
#pragma unroll
      for (int nj = 0; nj < 4; nj++) {
        acc[mi][nj] = __builtin_amdgcn_mfma_f32_16x16x32_bf16(
            af[mi][0], bfr[nj][0], acc[mi][nj], 0, 0, 0);
        acc[mi][nj] = __builtin_amdgcn_mfma_f32_16x16x32_bf16(
            af[mi][1], bfr[nj][1], acc[mi][nj], 0, 0, 0);
      }
  }
#pragma unroll
  for (int mi = 0; mi < 2; mi++) {
    int row = m0 + wm * 32 + mi * 16 + lh * 4;
#pragma unroll
    for (int nj = 0; nj < 4; nj++) {
      int col = n0 + wn * 64 + nj * 16 + lr;
      if (col >= N) continue;
      float b = bias[col];
#pragma unroll
      for (int r = 0; r < 4; r++) {
        float v = acc[mi][nj][r] + b;
        if (ACT) v = fmaxf(v, 0.f);
        if (OBF)
          ((unsigned short*)outp)[(size_t)(row + r) * N + col] = f2bf(v);
        else
          ((float*)outp)[(size_t)(row + r) * N + col] = v;
      }
    }
  }
}

// =================================================================
// GEMM (N=256 full rows) + residual + LayerNorm fused epilogue.
// BM=16, BN=256, grid 672. TOKOUT: also write NCHW token outputs.
// =================================================================
template <int WRITEQ, int TOKOUT>
__global__ __launch_bounds__(256) void gemm_ln(
    const unsigned short* __restrict__ A, const unsigned short* __restrict__ Wb,
    const float* __restrict__ bias, const float* __restrict__ g,
    const float* __restrict__ bta, float* __restrict__ x,
    unsigned short* __restrict__ xb, const unsigned short* __restrict__ peb,
    unsigned short* __restrict__ qb, int K, float* __restrict__ o3,
    float* __restrict__ o4, float* __restrict__ o5) {
  __shared__ unsigned short As[16 * 64];
  __shared__ unsigned short Ws[256 * 64];
  __shared__ float pred[4][16];
  __shared__ float qred[4][16];
  const int tid = threadIdx.x;
  const int swz = (blockIdx.x & 7) * 84 + (blockIdx.x >> 3);  // grid 672
  const int m0 = swz * 16;
  const int wid = tid >> 6, lane = tid & 63;  // wid = column quarter
  const int lr = lane & 15, lh = lane >> 4;
  const int r8 = tid >> 3, g8 = tid & 7;
  f32x4 acc[4];
#pragma unroll
  for (int i = 0; i < 4; i++) acc[i] = f32x4{0.f, 0.f, 0.f, 0.f};

  uint4 ra, rw[8];
  if (tid < 128)
    ra = *reinterpret_cast<const uint4*>(&A[(size_t)(m0 + r8) * K + g8 * 8]);
#pragma unroll
  for (int i = 0; i < 8; i++)
    rw[i] = *reinterpret_cast<const uint4*>(
        &Wb[(size_t)(r8 + i * 32) * K + g8 * 8]);

  for (int k0 = 0; k0 < K; k0 += 64) {
    if (k0) __syncthreads();
    if (tid < 128) store_chunk_bf(As, r8, g8, ra);
#pragma unroll
    for (int i = 0; i < 8; i++) store_chunk_bf(Ws, r8 + i * 32, g8, rw[i]);
    __syncthreads();
    int kn = k0 + 64;
    if (kn < K) {
      if (tid < 128)
        ra = *reinterpret_cast<const uint4*>(
            &A[(size_t)(m0 + r8) * K + kn + g8 * 8]);
#pragma unroll
      for (int i = 0; i < 8; i++)
        rw[i] = *reinterpret_cast<const uint4*>(
            &Wb[(size_t)(r8 + i * 32) * K + kn + g8 * 8]);
    }
    bf16x8 af[2];
    {
      int r = lr;
#pragma unroll
      for (int s = 0; s < 2; s++) {
        int gg2 = s * 4 + lh;
        af[s] =
            *reinterpret_cast<const bf16x8*>(&As[r * 64 + (gg2 ^ (r & 7)) * 8]);
      }
    }
#pragma unroll
    for (int nt = 0; nt < 4; nt++) {
      int r = wid * 64 + nt * 16 + lr;
      bf16x8 b0 =
          *reinterpret_cast<const bf16x8*>(&Ws[r * 64 + (lh ^ (r & 7)) * 8]);
      bf16x8 b1 = *reinterpret_cast<const bf16x8*>(
          &Ws[r * 64 + ((4 + lh) ^ (r & 7)) * 8]);
      acc[nt] =
          __builtin_amdgcn_mfma_f32_16x16x32_bf16(af[0], b0, acc[nt], 0, 0, 0);
      acc[nt] =
          __builtin_amdgcn_mfma_f32_16x16x32_bf16(af[1], b1, acc[nt], 0, 0, 0);
    }
  }

  const int rowl = lh * 4;
#pragma unroll
  for (int nt = 0; nt < 4; nt++) {
    int col = wid * 64 + nt * 16 + lr;
    float bs = bias[col];
#pragma unroll
    for (int r = 0; r < 4; r++)
      acc[nt][r] += bs + x[(size_t)(m0 + rowl + r) * 256 + col];
  }
  float sum[4];
#pragma unroll
  for (int r = 0; r < 4; r++) {
    float s = 0.f;
#pragma unroll
    for (int nt = 0; nt < 4; nt++) s += acc[nt][r];
#pragma unroll
    for (int o = 8; o > 0; o >>= 1) s += __shfl_xor(s, o);
    sum[r] = s;
  }
  if (lr == 0) {
#pragma unroll
    for (int r = 0; r < 4; r++) pred[wid][lh * 4 + r] = sum[r];
  }
  __syncthreads();
  float mu[4];
#pragma unroll
  for (int r = 0; r < 4; r++)
    mu[r] = (pred[0][lh * 4 + r] + pred[1][lh * 4 + r] + pred[2][lh * 4 + r] +
             pred[3][lh * 4 + r]) *
            (1.f / 256.f);
  float qs[4];
#pragma unroll
  for (int r = 0; r < 4; r++) {
    float q = 0.f;
#pragma unroll
    for (int nt = 0; nt < 4; nt++) {
      float d = acc[nt][r] - mu[r];
      q += d * d;
    }
#pragma unroll
    for (int o = 8; o > 0; o >>= 1) q += __shfl_xor(q, o);
    qs[r] = q;
  }
  if (lr == 0) {
#pragma unroll
    for (int r = 0; r < 4; r++) qred[wid][lh * 4 + r] = qs[r];
  }
  __syncthreads();
  float rstd[4];
#pragma unroll
  for (int r = 0; r < 4; r++)
    rstd[r] = rsqrtf((qred[0][lh * 4 + r] + qred[1][lh * 4 + r] +
                      qred[2][lh * 4 + r] + qred[3][lh * 4 + r]) *
                         (1.f / 256.f) +
                     EPSf);
  float oarr[4][4];
#pragma unroll
  for (int nt = 0; nt < 4; nt++) {
    int col = wid * 64 + nt * 16 + lr;
    float gw = g[col], bw = bta[col];
#pragma unroll
    for (int r = 0; r < 4; r++) {
      int row = m0 + rowl + r;
      size_t idx = (size_t)row * 256 + col;
      float o = (acc[nt][r] - mu[r]) * rstd[r] * gw + bw;
      x[idx] = o;
      xb[idx] = f2bf(o);
      if (WRITEQ) {
        size_t pc = idx - (row >= Ntok ? (size_t)Ntok * 256 : 0);
        qb[idx] = f2bf(o + bf2f(peb[pc]));
      }
      if (TOKOUT) oarr[nt][r] = o;
    }
  }
  if constexpr (TOKOUT) {
    __shared__ float tout[16][129];
    int bb = (m0 >= Ntok) ? 1 : 0;
    int n = m0 - bb * Ntok;
    float* outp;
    int osize, ostart;
    if (n < 4096) { outp = o3; osize = 4096; ostart = 0; }
    else if (n < 5120) { outp = o4; osize = 1024; ostart = 4096; }
    else { outp = o5; osize = 256; ostart = 5120; }
    int sp0 = n - ostart;
#pragma unroll
    for (int hh = 0; hh < 2; hh++) {
      __syncthreads();
      if ((wid >> 1) == hh) {
#pragma unroll
        for (int nt = 0; nt < 4; nt++) {
          int cl = (wid & 1) * 64 + nt * 16 + lr;
#pragma unroll
          for (int r = 0; r < 4; r++) tout[rowl + r][cl] = oarr[nt][r];
        }
      }
      __syncthreads();
      int cl = tid & 127, rh = tid >> 7;
      float* dst =
          outp + ((size_t)(bb * 256 + hh * 128 + cl)) * osize + sp0 + rh * 8;
#pragma unroll
      for (int i = 0; i < 8; i += 4) {
        float4 v4 = {tout[rh * 8 + i + 0][cl], tout[rh * 8 + i + 1][cl],
                     tout[rh * 8 + i + 2][cl], tout[rh * 8 + i + 3][cl]};
        *reinterpret_cast<float4*>(&dst[i]) = v4;
      }
    }
  }
}

// =================================================================
// FUSED: msda sampling + out-proj GEMM (K=256) + residual + LN1.
// grid 672, BM=16 rows. attn tile built in LDS (never hits HBM).
// =================================================================
__global__ __launch_bounds__(256) void msda_out_ln(
    const unsigned short* __restrict__ value, const float* __restrict__ off,
    const float* __restrict__ awl, const unsigned short* __restrict__ Wb,
    const float* __restrict__ bias, const float* __restrict__ g,
    const float* __restrict__ bta, float* __restrict__ x,
    unsigned short* __restrict__ xb) {
  __shared__ unsigned short Ws[256 * 64];      // 32KB; first 12288 = rec alias
  __shared__ unsigned short atile[4][16 * 64]; // 8KB
  __shared__ float pred[4][16];
  __shared__ float qred[4][16];
  const int tid = threadIdx.x;
  const int swz = (blockIdx.x & 7) * 84 + (blockIdx.x >> 3);  // grid 672
  const int m0 = swz * 16;
  const int wid = tid >> 6, lane = tid & 63;
  const int lr = lane & 15, lh = lane >> 4;
  const int r8 = tid >> 3, g8 = tid & 7;

  // W prologue loads (k=0) issued before msda work
  uint4 rw[8];
#pragma unroll
  for (int i = 0; i < 8; i++)
    rw[i] = *reinterpret_cast<const uint4*>(
        &Wb[(size_t)(r8 + i * 32) * 256 + g8 * 8]);

  // ---- phase 1: records for 128 groups (16 rows x 8 heads) ----
  unsigned short* rec = Ws;  // [128][12][8]: 4 ushort spat + 4 bf16 weight
  if (tid < 128) {
    int row = m0 + (tid >> 3);
    int h = tid & 7;
    int n = row % Ntok;
    int li0 = (n < 4096) ? 0 : ((n < 5120) ? 1 : 2);
    int start0 = (li0 == 0) ? 0 : ((li0 == 1) ? 4096 : 5120);
    int shift = 6 - li0;
    int Wn = 1 << shift;
    int sp = n - start0;
    int iy = sp >> shift;
    int ix = sp & (Wn - 1);
    float refx = (ix + 0.5f) / (float)Wn;
    float refy = (iy + 0.5f) / (float)Wn;
    const float* ap = awl + (size_t)row * 96 + h * 12;
    float lg[12];
    float mx = -1e30f;
#pragma unroll
    for (int j = 0; j < 12; j++) { lg[j] = ap[j]; mx = fmaxf(mx, lg[j]); }
    float ssum = 0.f;
#pragma unroll
    for (int j = 0; j < 12; j++) { lg[j] = expf(lg[j] - mx); ssum += lg[j]; }
    const float* op = off + (size_t)row * 192 + h * 24;
#pragma unroll
    for (int p = 0; p < 12; p++) {
      int li = p >> 2;
      int HWl = 64 >> li;
      float w = lg[p] / ssum;
      float ox = op[p * 2 + 0];
      float oy = op[p * 2 + 1];
      float lx = refx + ox / (float)HWl;
      float ly = refy + oy / (float)HWl;
      float fx = lx * (float)HWl - 0.5f;
      float fy = ly * (float)HWl - 0.5f;
      float x0f = floorf(fx), y0f = floorf(fy);
      float wx = fx - x0f, wy = fy - y0f;
      int ix0 = (int)x0f, iy0 = (int)y0f;
      unsigned short sp4[4], w4[4];
#pragma unroll
      for (int cr = 0; cr < 4; cr++) {
        int cx = ix0 + (cr & 1);
        int cy = iy0 + (cr >> 1);
        bool valid = (cx >= 0) & (cx < HWl) & (cy >= 0) & (cy < HWl);
        float wc = ((cr & 1) ? wx : 1.f - wx) * ((cr >> 1) ? wy : 1.f - wy);
        int cxc = min(max(cx, 0), HWl - 1);
        int cyc = min(max(cy, 0), HWl - 1);
        sp4[cr] = (unsigned short)(cyc * HWl + cxc);
        w4[cr] = f2bf(valid ? (w * wc) : 0.f);
      }
      *reinterpret_cast<uint2*>(&rec[(tid * 12 + p) * 8]) =
          *reinterpret_cast<const uint2*>(sp4);
      *reinterpret_cast<uint2*>(&rec[(tid * 12 + p) * 8 + 4]) =
          *reinterpret_cast<const uint2*>(w4);
    }
  }
  __syncthreads();
  // ---- phase 2: gather -> atile (bf16, swizzled), uint4-vectorized ----
  {
    int gq = tid >> 1;       // group 0..127
    int half = tid & 1;      // which 16-channel half of the head's 32
    int rr = gq >> 3;        // local row 0..15
    int row = m0 + rr;
    int h = gq & 7;
    int b = (row >= Ntok) ? 1 : 0;
    int coff = h * 32 + half * 16;
    int base0 = (b * Ntok + 0) * 256 + coff;
    int base1 = (b * Ntok + 4096) * 256 + coff;
    int base2 = (b * Ntok + 5120) * 256 + coff;
    float acc[16];
#pragma unroll
    for (int j = 0; j < 16; j++) acc[j] = 0.f;
    const unsigned short* rp = rec + gq * 96;
#pragma unroll
    for (int p = 0; p < 12; p++) {
      int li = p >> 2;
      int base = (li == 0) ? base0 : ((li == 1) ? base1 : base2);
      unsigned short sp4[4], w4[4];
      *reinterpret_cast<uint2*>(sp4) =
          *reinterpret_cast<const uint2*>(&rp[p * 8]);
      *reinterpret_cast<uint2*>(w4) =
          *reinterpret_cast<const uint2*>(&rp[p * 8 + 4]);
#pragma unroll
      for (int cr = 0; cr < 4; cr++) {
        float w = bf2f(w4[cr]);
        const unsigned short* vsrc = value + base + (int)sp4[cr] * 256;
        uint4 va = *reinterpret_cast<const uint4*>(vsrc);
        uint4 vb4 = *reinterpret_cast<const uint4*>(vsrc + 8);
        unsigned uu[8] = {va.x, va.y, va.z, va.w, vb4.x, vb4.y, vb4.z, vb4.w};
#pragma unroll
        for (int j = 0; j < 8; j++) {
          acc[j * 2 + 0] += w * bf2f((unsigned short)(uu[j] & 0xffff));
          acc[j * 2 + 1] += w * bf2f((unsigned short)(uu[j] >> 16));
        }
      }
    }
#pragma unroll
    for (int j = 0; j < 8; j++) {
      int c0 = coff + j * 2;
      int kc = c0 >> 6;
      int cc = c0 & 63;
      int ggr = cc >> 3, el = cc & 7;
      unsigned outw =
          (unsigned)f2bf(acc[j * 2]) | ((unsigned)f2bf(acc[j * 2 + 1]) << 16);
      *reinterpret_cast<unsigned*>(
          &atile[kc][rr * 64 + ((ggr ^ (rr & 7)) * 8) + el]) = outw;
    }
  }
  __syncthreads();  // rec dead; Ws now usable for W tiles

  // ---- phase 3: K=256 GEMM from atile/Ws + LN epilogue ----
  f32x4 acc[4];
#pragma unroll
  for (int i = 0; i < 4; i++) acc[i] = f32x4{0.f, 0.f, 0.f, 0.f};
  for (int k0 = 0; k0 < 256; k0 += 64) {
    if (k0) __syncthreads();
#pragma unroll
    for (int i = 0; i < 8; i++) store_chunk_bf(Ws, r8 + i * 32, g8, rw[i]);
    __syncthreads();
    int kn = k0 + 64;
    if (kn < 256) {
#pragma unroll
      for (int i = 0; i < 8; i++)
        rw[i] = *reinterpret_cast<const uint4*>(
            &Wb[(size_t)(r8 + i * 32) * 256 + kn + g8 * 8]);
    }
    bf16x8 af[2];
    {
      int r = lr;
#pragma unroll
      for (int s = 0; s < 2; s++) {
        int gg2 = s * 4 + lh;
        af[s] = *reinterpret_cast<const bf16x8*>(
            &atile[k0 >> 6][r * 64 + (gg2 ^ (r & 7)) * 8]);
      }
    }
#pragma unroll
    for (int nt = 0; nt < 4; nt++) {
      int r = wid * 64 + nt * 16 + lr;
      bf16x8 b0 =
          *reinterpret_cast<const bf16x8*>(&Ws[r * 64 + (lh ^ (r & 7)) * 8]);
      bf16x8 b1 = *reinterpret_cast<const bf16x8*>(
          &Ws[r * 64 + ((4 + lh) ^ (r & 7)) * 8]);
      acc[nt] =
          __builtin_amdgcn_mfma_f32_16x16x32_bf16(af[0], b0, acc[nt], 0, 0, 0);
      acc[nt] =
          __builtin_amdgcn_mfma_f32_16x16x32_bf16(af[1], b1, acc[nt], 0, 0, 0);
    }
  }

  const int rowl = lh * 4;
#pragma unroll
  for (int nt = 0; nt < 4; nt++) {
    int col = wid * 64 + nt * 16 + lr;
    float bs = bias[col];
#pragma unroll
    for (int r = 0; r < 4; r++)
      acc[nt][r] += bs + x[(size_t)(m0 + rowl + r) * 256 + col];
  }
  float sum[4];
#pragma unroll
  for (int r = 0; r < 4; r++) {
    float s = 0.f;
#pragma unroll
    for (int nt = 0; nt < 4; nt++) s += acc[nt][r];
#pragma unroll
    for (int o = 8; o > 0; o >>= 1) s += __shfl_xor(s, o);
    sum[r] = s;
  }
  if (lr == 0) {
#pragma unroll
    for (int r = 0; r < 4; r++) pred[wid][lh * 4 + r] = sum[r];
  }
  __syncthreads();
  float mu[4];
#pragma unroll
  for (int r = 0; r < 4; r++)
    mu[r] = (pred[0][lh * 4 + r] + pred[1][lh * 4 + r] + pred[2][lh * 4 + r] +
             pred[3][lh * 4 + r]) *
            (1.f / 256.f);
  float qs[4];
#pragma unroll
  for (int r = 0; r < 4; r++) {
    float q = 0.f;
#pragma unroll
    for (int nt = 0; nt < 4; nt++) {
      float d = acc[nt][r] - mu[r];
      q += d * d;
    }
#pragma unroll
    for (int o = 8; o > 0; o >>= 1) q += __shfl_xor(q, o);
    qs[r] = q;
  }
  if (lr == 0) {
#pragma unroll
    for (int r = 0; r < 4; r++) qred[wid][lh * 4 + r] = qs[r];
  }
  __syncthreads();
  float rstd[4];
#pragma unroll
  for (int r = 0; r < 4; r++)
    rstd[r] = rsqrtf((qred[0][lh * 4 + r] + qred[1][lh * 4 + r] +
                      qred[2][lh * 4 + r] + qred[3][lh * 4 + r]) *
                         (1.f / 256.f) +
                     EPSf);
#pragma unroll
  for (int nt = 0; nt < 4; nt++) {
    int col = wid * 64 + nt * 16 + lr;
    float gw = g[col], bw = bta[col];
#pragma unroll
    for (int r = 0; r < 4; r++) {
      int row = m0 + rowl + r;
      size_t idx = (size_t)row * 256 + col;
      float o = (acc[nt][r] - mu[r]) * rstd[r] * gw + bw;
      x[idx] = o;
      xb[idx] = f2bf(o);
    }
  }
}

// -------- fused head GEMMs, BM=32: val (0..671) + off/aw (672..1679) --------
__global__ __launch_bounds__(256) void gemm_head(
    const unsigned short* __restrict__ xb, const unsigned short* __restrict__ qb,
    const unsigned short* __restrict__ wv, const unsigned short* __restrict__ wo,
    const float* __restrict__ valB, const float* __restrict__ offB,
    const float* __restrict__ awB, unsigned short* __restrict__ valO,
    float* __restrict__ offO, float* __restrict__ awO) {
  __shared__ unsigned short As[32 * 64];
  __shared__ unsigned short Ws[128 * 64];
  const int tid = threadIdx.x;
  const int swz = (blockIdx.x & 7) * 210 + (blockIdx.x >> 3);  // grid 1680
  const bool isval = swz < 672;
  const unsigned short* A;
  const unsigned short* W;
  int m0, n0, Nn;
  if (isval) {
    A = xb; W = wv; Nn = 256;
    m0 = (swz >> 1) * 32; n0 = (swz & 1) * 128;
  } else {
    int s = swz - 672;
    A = qb; W = wo; Nn = 288;
    m0 = (s / 3) * 32; n0 = (s % 3) * 128;
  }
  const int wid = tid >> 6, lane = tid & 63;
  const int wm = wid >> 1, wn = wid & 1;
  const int lr = lane & 15, lh = lane >> 4;
  const int r8 = tid >> 3, g8 = tid & 7;
  f32x4 acc[4];
#pragma unroll
  for (int j = 0; j < 4; j++) acc[j] = f32x4{0.f, 0.f, 0.f, 0.f};

  uint4 ra, rw[4];
  const uint4 z4 = uint4{0, 0, 0, 0};
  ra = *reinterpret_cast<const uint4*>(&A[(size_t)(m0 + r8) * 256 + g8 * 8]);
#pragma unroll
  for (int i = 0; i < 4; i++) {
    int n = n0 + r8 + i * 32;
    rw[i] = (n < Nn) ? *reinterpret_cast<const uint4*>(
                           &W[(size_t)n * 256 + g8 * 8])
                     : z4;
  }

  for (int k0 = 0; k0 < 256; k0 += 64) {
    if (k0) __syncthreads();
    store_chunk_bf(As, r8, g8, ra);
#pragma unroll
    for (int i = 0; i < 4; i++) store_chunk_bf(Ws, r8 + i * 32, g8, rw[i]);
    __syncthreads();
    int kn = k0 + 64;
    if (kn < 256) {
      ra = *reinterpret_cast<const uint4*>(
          &A[(size_t)(m0 + r8) * 256 + kn + g8 * 8]);
#pragma unroll
      for (int i = 0; i < 4; i++) {
        int n = n0 + r8 + i * 32;
        rw[i] = (n < Nn) ? *reinterpret_cast<const uint4*>(
                               &W[(size_t)n * 256 + kn + g8 * 8])
                         : z4;
      }
    }
    bf16x8 af[2];
    {
      int r = wm * 16 + lr;
#pragma unroll
      for (int s = 0; s < 2; s++) {
        int gg2 = s * 4 + lh;
        af[s] =
            *reinterpret_cast<const bf16x8*>(&As[r * 64 + (gg2 ^ (r & 7)) * 8]);
      }
    }
#pragma unroll
    for (int nj = 0; nj < 4; nj++) {
      int r = wn * 64 + nj * 16 + lr;
      bf16x8 b0 =
          *reinterpret_cast<const bf16x8*>(&Ws[r * 64 + (lh ^ (r & 7)) * 8]);
      bf16x8 b1 = *reinterpret_cast<const bf16x8*>(
          &Ws[r * 64 + ((4 + lh) ^ (r & 7)) * 8]);
      acc[nj] =
          __builtin_amdgcn_mfma_f32_16x16x32_bf16(af[0], b0, acc[nj], 0, 0, 0);
      acc[nj] =
          __builtin_amdgcn_mfma_f32_16x16x32_bf16(af[1], b1, acc[nj], 0, 0, 0);
    }
  }
  const int row0 = m0 + wm * 16 + lh * 4;
#pragma unroll
  for (int nj = 0; nj < 4; nj++) {
    int col = n0 + wn * 64 + nj * 16 + lr;
    if (isval) {
      float b = valB[col];
#pragma unroll
      for (int r = 0; r < 4; r++)
        valO[(size_t)(row0 + r) * 256 + col] = f2bf(acc[nj][r] + b);
    } else {
      if (col >= 288) continue;
      float b = (col < 192) ? offB[col] : awB[col - 192];
#pragma unroll
      for (int r = 0; r < 4; r++) {
        float v = acc[nj][r] + b;
        if (col < 192)
          offO[(size_t)(row0 + r) * 192 + col] = v;
        else
          awO[(size_t)(row0 + r) * 96 + col - 192] = v;
      }
    }
  }
}

// ------------- implicit-GEMM 3x3 conv, BM=128 x BN=128, grid 512 -------------
// + fused GN partial sums. Measured-best config (R23): do not touch.
__global__ __launch_bounds__(256) void conv3x3_mfma(
    const unsigned short* __restrict__ T, const unsigned short* __restrict__ Wt,
    const float* __restrict__ bias, unsigned short* __restrict__ out,
    float* __restrict__ gnpart) {
  __shared__ unsigned short As[128 * 64];
  __shared__ unsigned short Ws[128 * 64];
  __shared__ float gs[2][2][4][2];
  __shared__ float gq2[2][2][4][2];
  const int tid = threadIdx.x;
  const int swz = (blockIdx.x & 7) * 64 + (blockIdx.x >> 3);  // grid 512
  const int m0 = (swz >> 1) * 128, n0 = (swz & 1) * 128;
  const int b = m0 >> 14;
  const int p0 = m0 & 16383;
  const int y = p0 >> 7;
  const int x0 = p0 & 127;  // always 0: tile = one full image row
  const int wid = tid >> 6, lane = tid & 63;
  const int wm = wid >> 1, wn = wid & 1;
  const int lr = lane & 15, lh = lane >> 4;
  const int r8 = tid >> 3, g8 = tid & 7;
  f32x4 acc[4][4];
#pragma unroll
  for (int i = 0; i < 4; i++)
#pragma unroll
    for (int j = 0; j < 4; j++) acc[i][j] = f32x4{0.f, 0.f, 0.f, 0.f};

  uint4 ra[4], rw[4];
  auto loadA = [&](int kc, uint4* r) {
    int tap = kc >> 2;
    int cb = (kc & 3) * 64;
    int dy = tap / 3 - 1, dx = tap % 3 - 1;
    int yy = y + dy;
#pragma unroll
    for (int i = 0; i < 4; i++) {
      int row = r8 + i * 32;
      int xx = x0 + row + dx;
      uint4 v = uint4{0, 0, 0, 0};
      if (yy >= 0 && yy < 128 && xx >= 0 && xx < 128)
        v = *reinterpret_cast<const uint4*>(
            &T[((size_t)(b * 16384 + yy * 128 + xx)) * 256 + cb + g8 * 8]);
      r[i] = v;
    }
  };
  auto loadW = [&](int kc, uint4* r) {
#pragma unroll
    for (int i = 0; i < 4; i++)
      r[i] = *reinterpret_cast<const uint4*>(
          &Wt[(size_t)(n0 + r8 + i * 32) * 2304 + kc * 64 + g8 * 8]);
  };
  loadA(0, ra);
  loadW(0, rw);

  for (int kc = 0; kc < 36; kc++) {
    if (kc) __syncthreads();
#pragma unroll
    for (int i = 0; i < 4; i++) store_chunk_bf(As, r8 + i * 32, g8, ra[i]);
#pragma unroll
    for (int i = 0; i < 4; i++) store_chunk_bf(Ws, r8 + i * 32, g8, rw[i]);
    __syncthreads();
    if (kc + 1 < 36) {
      loadA(kc + 1, ra);
      loadW(kc + 1, rw);
    }
    bf16x8 af[4][2], bfr[4][2];
#pragma unroll
    for (int mi = 0; mi < 4; mi++) {
      int r = wm * 64 + mi * 16 + lr;
#pragma unroll
      for (int s = 0; s < 2; s++) {
        int g = s * 4 + lh;
        af[mi][s] =
            *reinterpret_cast<const bf16x8*>(&As[r * 64 + (g ^ (r & 7)) * 8]);
      }
    }
#pragma unroll
    for (int nj = 0; nj < 4; nj++) {
      int r = wn * 64 + nj * 16 + lr;
#pragma unroll
      for (int s = 0; s < 2; s++) {
        int g = s * 4 + lh;
        bfr[nj][s] =
            *reinterpret_cast<const bf16x8*>(&Ws[r * 64 + (g ^ (r & 7)) * 8]);
      }
    }
#pragma unroll
    for (int mi = 0; mi < 4; mi++)
#pragma unroll
      for (int nj = 0; nj < 4; nj++) {
        acc[mi][nj] = __builtin_amdgcn_mfma_f32_16x16x32_bf16(
            af[mi][0], bfr[nj][0], acc[mi][nj], 0, 0, 0);
        acc[mi][nj] = __builtin_amdgcn_mfma_f32_16x16x32_bf16(
            af[mi][1], bfr[nj][1], acc[mi][nj], 0, 0, 0);
      }
  }
  // epilogue: write bf16 output and accumulate GN partials per column-group
  float gsumv[4] = {0.f, 0.f, 0.f, 0.f};
  float gsqv[4] = {0.f, 0.f, 0.f, 0.f};
#pragma unroll
  for (int mi = 0; mi < 4; mi++) {
    int row = m0 + wm * 64 + mi * 16 + lh * 4;
#pragma unroll
    for (int nj = 0; nj < 4; nj++) {
      int col = n0 + wn * 64 + nj * 16 + lr;
      float bv = bias[col];
#pragma unroll
      for (int r = 0; r < 4; r++) {
        unsigned short ob = f2bf(acc[mi][nj][r] + bv);
        out[(size_t)(row + r) * 256 + col] = ob;
        float vv = bf2f(ob);
        gsumv[nj] += vv;
        gsqv[nj] += vv * vv;
      }
    }
  }
  // reduce over lanes sharing (lr>>3): xor masks 1,2,4 (lr low) + 16,32 (lh)
#pragma unroll
  for (int nj = 0; nj < 4; nj++) {
    float s = gsumv[nj], q = gsqv[nj];
    s += __shfl_xor(s, 1);  q += __shfl_xor(q, 1);
    s += __shfl_xor(s, 2);  q += __shfl_xor(q, 2);
    s += __shfl_xor(s, 4);  q += __shfl_xor(q, 4);
    s += __shfl_xor(s, 16); q += __shfl_xor(q, 16);
    s += __shfl_xor(s, 32); q += __shfl_xor(q, 32);
    gsumv[nj] = s;
    gsqv[nj] = q;
  }
  if ((lane & 7) == 0 && lh == 0) {
    int half = (lane >> 3) & 1;
#pragma unroll
    for (int nj = 0; nj < 4; nj++) {
      gs[wm][wn][nj][half] = gsumv[nj];
      gq2[wm][wn][nj][half] = gsqv[nj];
    }
  }
  __syncthreads();
  if (tid < 16) {
    int wn2 = tid >> 3, nj = (tid >> 1) & 3, half = tid & 1;
    float s = gs[0][wn2][nj][half] + gs[1][wn2][nj][half];
    float q = gq2[0][wn2][nj][half] + gq2[1][wn2][nj][half];
    int g = (n0 >> 3) + tid;  // group in [0,32)
    int t = swz >> 1;         // pixel tile incl. batch, [0,256)
    gnpart[((size_t)t * 32 + g) * 2 + 0] = s;
    gnpart[((size_t)t * 32 + g) * 2 + 1] = q;
  }
}

// ------------- TN GEMM (1x1 lateral conv) + fused bilinear upsample-add -------------
__global__ __launch_bounds__(256) void gemm_tn_mfma(
    const float* __restrict__ A, const unsigned short* __restrict__ Wb,
    const float* __restrict__ bias, const float* __restrict__ x,
    unsigned short* __restrict__ out) {
  __shared__ unsigned short As[64 * 64];
  __shared__ unsigned short Ws[128 * 64];
  const int tid = threadIdx.x;
  const int nwg = gridDim.x;  // 1024
  const int swz = (blockIdx.x & 7) * (nwg >> 3) + (blockIdx.x >> 3);
  const int m0 = (swz >> 1) * 64, n0 = (swz & 1) * 128;
  const int b = m0 >> 14;
  const int p0 = m0 & 16383;
  const int wid = tid >> 6, lane = tid & 63;
  const int wm = wid >> 1, wn = wid & 1;
  const int lr = lane & 15, lh = lane >> 4;
  const int r8 = tid >> 3, g8 = tid & 7;
  const int arow = tid & 63, agb = tid >> 6;
  f32x4 acc[2][4];
#pragma unroll
  for (int i = 0; i < 2; i++)
#pragma unroll
    for (int j = 0; j < 4; j++) acc[i][j] = f32x4{0.f, 0.f, 0.f, 0.f};

  float va[16];
  uint4 rw[4];
  auto loadA = [&](int k0, float* v) {
#pragma unroll
    for (int i = 0; i < 2; i++) {
      int g = agb + i * 4;
#pragma unroll
      for (int j = 0; j < 8; j++)
        v[i * 8 + j] =
            A[(size_t)(b * 256 + k0 + g * 8 + j) * 16384 + p0 + arow];
    }
  };
  auto loadW = [&](int k0, uint4* r) {
#pragma unroll
    for (int i = 0; i < 4; i++)
      r[i] = *reinterpret_cast<const uint4*>(
          &Wb[(size_t)(n0 + r8 + i * 32) * 256 + k0 + g8 * 8]);
  };
  loadA(0, va);
  loadW(0, rw);

  for (int k0 = 0; k0 < 256; k0 += 64) {
    if (k0) __syncthreads();
#pragma unroll
    for (int i = 0; i < 2; i++)
      store_chunk_f32(As, arow, agb + i * 4, &va[i * 8]);
#pragma unroll
    for (int i = 0; i < 4; i++) store_chunk_bf(Ws, r8 + i * 32, g8, rw[i]);
    __syncthreads();
    int kn = k0 + 64;
    if (kn < 256) {
      loadA(kn, va);
      loadW(kn, rw);
    }
    bf16x8 af[2][2], bfr[4][2];
#pragma unroll
    for (int mi = 0; mi < 2; mi++) {
      int r = wm * 32 + mi * 16 + lr;
#pragma unroll
      for (int s = 0; s < 2; s++) {
        int g = s * 4 + lh;
        af[mi][s] =
            *reinterpret_cast<const bf16x8*>(&As[r * 64 + (g ^ (r & 7)) * 8]);
      }
    }
#pragma unroll
    for (int nj = 0; nj < 4; nj++) {
      int r = wn * 64 + nj * 16 + lr;
#pragma unroll
      for (int s = 0; s < 2; s++) {
        int g = s * 4 + lh;
        bfr[nj][s] =
            *reinterpret_cast<const bf16x8*>(&Ws[r * 64 + (g ^ (r & 7)) * 8]);
      }
    }
#pragma unroll
    for (int mi = 0; mi < 2; mi++)
#pragma unroll
      for (int nj = 0; nj < 4; nj++) {
        acc[mi][nj] = __builtin_amdgcn_mfma_f32_16x16x32_bf16(
            af[mi][0], bfr[nj][0], acc[mi][nj], 0, 0, 0);
        acc[mi][nj] = __builtin_amdgcn_mfma_f32_16x16x32_bf16(
            af[mi][1], bfr[nj][1], acc[mi][nj], 0, 0, 0);
      }
  }
  const float* xbse = x + (size_t)b * Ntok * 256;
#pragma unroll
  for (int mi = 0; mi < 2; mi++) {
    int row0 = m0 + wm * 32 + mi * 16 + lh * 4;
#pragma unroll
    for (int r = 0; r < 4; r++) {
      int p = (row0 + r) & 16383;
      int Y = p >> 7, X = p & 127;
      float yc = Y * 0.5f - 0.25f;
      float y0f = floorf(yc);
      float wy = yc - y0f;
      int y0 = (int)y0f;
      int y0c = min(max(y0, 0), 63), y1c = min(max(y0 + 1, 0), 63);
      float xc = X * 0.5f - 0.25f;
      float x0f = floorf(xc);
      float wx = xc - x0f;
      int xq0 = (int)x0f;
      int x0c = min(max(xq0, 0), 63), x1c = min(max(xq0 + 1, 0), 63);
      const float* r00 = xbse + (size_t)(y0c * 64 + x0c) * 256;
      const float* r01 = xbse + (size_t)(y0c * 64 + x1c) * 256;
      const float* r10 = xbse + (size_t)(y1c * 64 + x0c) * 256;
      const float* r11 = xbse + (size_t)(y1c * 64 + x1c) * 256;
#pragma unroll
      for (int nj = 0; nj < 4; nj++) {
        int col = n0 + wn * 64 + nj * 16 + lr;
        float up = (1.f - wy) * ((1.f - wx) * r00[col] + wx * r01[col]) +
                   wy * ((1.f - wx) * r10[col] + wx * r11[col]);
        out[(size_t)(row0 + r) * 256 + col] =
            f2bf(acc[mi][nj][r] + bias[col] + up);
      }
    }
  }
}

// ---------------- GN final: parallel reduce 128 tile-partials per (b,g) ----------------
// grid 64 blocks (one per b*32+g), 128 threads: thread t loads tile t's partial.
__global__ __launch_bounds__(128) void gn_final(const float* __restrict__ part,
                                                float* __restrict__ stats) {
  __shared__ float rs[128], rq[128];
  int bg = blockIdx.x;  // b*32+g
  int b = bg >> 5, g = bg & 31;
  int tid = threadIdx.x;
  int t = b * 128 + tid;
  rs[tid] = part[((size_t)t * 32 + g) * 2 + 0];
  rq[tid] = part[((size_t)t * 32 + g) * 2 + 1];
  __syncthreads();
  for (int st = 64; st > 0; st >>= 1) {
    if (tid < st) {
      rs[tid] += rs[tid + st];
      rq[tid] += rq[tid + st];
    }
    __syncthreads();
  }
  if (tid == 0) {
    float mu = rs[0] * (1.f / 131072.f);
    float var = rq[0] * (1.f / 131072.f) - mu * mu;
    stats[bg * 2 + 0] = mu;
    stats[bg * 2 + 1] = rsqrtf(var + EPSf);
  }
}

// ---------------- GN apply + GELU + transpose to NCHW (bf16 input) ----------------
__global__ void gn_apply(const unsigned short* __restrict__ s,
                         const float* __restrict__ stats,
                         const float* __restrict__ gg,
                         const float* __restrict__ gb,
                         float* __restrict__ out) {
  __shared__ float tile[32][33];
  int p0 = blockIdx.x * 32, c0 = blockIdx.y * 32, b = blockIdx.z;
  int tx = threadIdx.x, tyy = threadIdx.y;
  int c = c0 + tx;
  float mu = stats[(b * 32 + (c >> 3)) * 2 + 0];
  float rstd = stats[(b * 32 + (c >> 3)) * 2 + 1];
  float gw = gg[c], bw = gb[c];
  for (int i = tyy; i < 32; i += 8) {
    float v = bf2f(s[((size_t)(b * 16384 + p0 + i)) * 256 + c]);
    v = (v - mu) * rstd * gw + bw;
    v = 0.5f * v * (1.f + erff(v * 0.70710678118654752f));
    tile[i][tx] = v;
  }
  __syncthreads();
  for (int i = tyy; i < 32; i += 8)
    out[((size_t)(b * 256 + c0 + i)) * 16384 + p0 + tx] = tile[tx][i];
}

// ---------------- launcher ----------------
extern "C" void kernel_launch(void* const* d_in, const int* in_sizes, int n_in,
                              void* d_out, int out_size, void* d_ws,
                              size_t ws_size, hipStream_t stream) {
  (void)in_sizes; (void)n_in; (void)out_size; (void)ws_size;
  const float* res2  = (const float*)d_in[0];
  const float* res3  = (const float*)d_in[1];
  const float* res4  = (const float*)d_in[2];
  const float* res5  = (const float*)d_in[3];
  const float* lemb  = (const float*)d_in[4];
  const float* off_W = (const float*)d_in[5];
  const float* off_b = (const float*)d_in[6];
  const float* aw_W  = (const float*)d_in[7];
  const float* aw_b  = (const float*)d_in[8];
  const float* val_W = (const float*)d_in[9];
  const float* val_b = (const float*)d_in[10];
  const float* out_W = (const float*)d_in[11];
  const float* out_b = (const float*)d_in[12];
  const float* ln1_g = (const float*)d_in[13];
  const float* ln1_b = (const float*)d_in[14];
  const float* fc1_W = (const float*)d_in[15];
  const float* fc1_b = (const float*)d_in[16];
  const float* fc2_W = (const float*)d_in[17];
  const float* fc2_b = (const float*)d_in[18];
  const float* ln2_g = (const float*)d_in[19];
  const float* ln2_b = (const float*)d_in[20];
  const float* lat_W = (const float*)d_in[21];
  const float* lat_b = (const float*)d_in[22];
  const float* sm_W  = (const float*)d_in[23];
  const float* sm_b  = (const float*)d_in[24];
  const float* gn_g  = (const float*)d_in[25];
  const float* gn_b  = (const float*)d_in[26];

  float* ws = (float*)d_ws;
  // layout (float units); bf16 buffers take count/2 floats
  float*          x      = ws;                               // (2752512)
  unsigned short* xb     = (unsigned short*)(ws + 2752512);  // (1376256 bf16)
  unsigned short* peb    = (unsigned short*)(ws + 4128768);  // (688128 bf16)
  unsigned short* qb     = (unsigned short*)(ws + 4816896);  // (1376256 bf16)
  unsigned short* valueb = (unsigned short*)(ws + 6193152);  // (1376256 bf16)
  float*          offb   = ws + 7569408;                     // (2064384 f)
  float*          awl    = ws + 9633792;                     // (1032192 f)
  unsigned short* hb     = (unsigned short*)(ws + 14794752); // (5505024 bf16)
  unsigned short* tbuf   = hb;  // conv input aliases hb (dead after layers)
  unsigned short* wtbuf  = (unsigned short*)(ws + 20299776); // 589824 bf16 -> ends 20594688f
  unsigned short* wbf    = (unsigned short*)(ws + 20596864); // 6*WL+65536 bf16
  unsigned short* wlat   = wbf + (size_t)6 * WL;
  unsigned short* sbufb  = (unsigned short*)ws;  // conv out bf16, dead x span
  // gnpart/gnstat alias offb (dead after last layer's msda_out_ln)
  float*          gnpart = ws + 7569408;                     // 16384 floats
  float*          gnstat = ws + 7585792;                     // 128 floats

  float* out_s  = (float*)d_out;
  float* out_o3 = out_s + (size_t)Bn * Cc * HW2;
  float* out_o4 = out_o3 + (size_t)Bn * Cc * 4096;
  float* out_o5 = out_o4 + (size_t)Bn * Cc * 1024;

  const int M = Bn * Ntok;  // 10752

  setup_all<<<7664, 256, 0, stream>>>(res3, res4, res5, lemb, x, xb, qb, peb,
                                      val_W, off_W, aw_W, out_W, fc1_W, fc2_W,
                                      lat_W, sm_W, wbf, wlat, wtbuf);

  for (int l = 0; l < 6; l++) {
    const unsigned short* wl = wbf + (size_t)l * WL;
    gemm_head<<<1680, 256, 0, stream>>>(
        xb, qb, wl + 0, wl + 65536, val_b + l * 256, off_b + l * 192,
        aw_b + l * 96, valueb, offb, awl);
    msda_out_ln<<<672, 256, 0, stream>>>(
        valueb, offb, awl, wl + 139264, out_b + l * 256, ln1_g + l * 256,
        ln1_b + l * 256, x, xb);
    gemm_mfma_b<1, 1><<<1344, 256, 0, stream>>>(
        xb, wl + 204800, fc1_b + l * 1024, hb, M, 1024, 256, 8);
    if (l < 5)
      gemm_ln<1, 0><<<672, 256, 0, stream>>>(
          hb, wl + 466944, fc2_b + l * 256, ln2_g + l * 256, ln2_b + l * 256,
          x, xb, peb, qb, 1024, nullptr, nullptr, nullptr);
    else
      gemm_ln<0, 1><<<672, 256, 0, stream>>>(
          hb, wl + 466944, fc2_b + l * 256, ln2_g + l * 256, ln2_b + l * 256,
          x, xb, peb, qb, 1024, out_o3, out_o4, out_o5);
  }

  // FPN tail: lat-GEMM with fused upsample-add (reads x), then conv+GN-partials
  gemm_tn_mfma<<<1024, 256, 0, stream>>>(res2, wlat, lat_b, x, tbuf);
  conv3x3_mfma<<<512, 256, 0, stream>>>(tbuf, wtbuf, sm_b, sbufb, gnpart);
  gn_final<<<64, 128, 0, stream>>>(gnpart, gnstat);
  gn_apply<<<dim3(512, 8, 2), dim3(32, 8), 0, stream>>>(sbufb, gnstat, gn_g,
                                                        gn_b, out_s);
}